// Round 7
// baseline (178.648 us; speedup 1.0000x reference)
//
#include <hip/hip_runtime.h>

#define MAXM 16
#define NL_CAP 768
#define THETA 0.1f
#define LTK 72

typedef unsigned short u16;
typedef u16 u16x8 __attribute__((ext_vector_type(8)));
typedef u16 u16x4 __attribute__((ext_vector_type(4)));
typedef __bf16 bf16x8 __attribute__((ext_vector_type(8)));
typedef float f32x4 __attribute__((ext_vector_type(4)));

// ==================== f32 -> bf16 (RNE) ====================

__device__ __forceinline__ u16 f2bf(float f) {
    unsigned u = __float_as_uint(f);
    return (u16)((u + 0x7fffu + ((u >> 16) & 1u)) >> 16);
}

__global__ __launch_bounds__(256)
void conv_k(const float* __restrict__ x, const float* __restrict__ b,
            u16* __restrict__ xb, u16* __restrict__ bb, long nx, long nb)
{
    long i = ((long)blockIdx.x * 256 + threadIdx.x) * 4;
    if (i < nx) {
        float4 v = *(const float4*)&x[i];
        u16x4 o = {f2bf(v.x), f2bf(v.y), f2bf(v.z), f2bf(v.w)};
        *(u16x4*)&xb[i] = o;
    }
    if (i < nb) {
        float4 v = *(const float4*)&b[i];
        u16x4 o = {f2bf(v.x), f2bf(v.y), f2bf(v.z), f2bf(v.w)};
        *(u16x4*)&bb[i] = o;
    }
}

// ==================== bf16 MFMA GEMM: C = A * B^T ====================
// A [M,K] bf16, B [N,K] bf16, C [M,N] f32. M,N%128==0, K%32==0.
// 128x128 tile, 4 waves x (64x64 via 4x4 mfma_f32_16x16x32_bf16).

__global__ __launch_bounds__(256)
void bgemm_k(const u16* __restrict__ A, const u16* __restrict__ B,
             float* __restrict__ C, int Mdim, int Ndim, int Kdim)
{
    __shared__ u16 Al[128 * LTK];
    __shared__ u16 Bl[128 * LTK];

    const int tid = threadIdx.x;
    const int bm = blockIdx.y * 128, bn = blockIdx.x * 128;
    const int wv = tid >> 6, ln = tid & 63;
    const int wr = (wv >> 1) * 64, wc = (wv & 1) * 64;
    const int fr = ln & 15, fk = (ln >> 4) * 8;

    const int r0 = tid >> 2, c0 = (tid & 3) * 8;
    const u16* Ap0 = A + (size_t)(bm + r0) * Kdim + c0;
    const u16* Ap1 = Ap0 + (size_t)64 * Kdim;
    const u16* Bp0 = B + (size_t)(bn + r0) * Kdim + c0;
    const u16* Bp1 = Bp0 + (size_t)64 * Kdim;

    f32x4 acc[4][4];
#pragma unroll
    for (int m = 0; m < 4; ++m)
#pragma unroll
        for (int n = 0; n < 4; ++n) acc[m][n] = (f32x4)0.f;

    u16x8 ra0 = *(const u16x8*)Ap0;
    u16x8 ra1 = *(const u16x8*)Ap1;
    u16x8 rb0 = *(const u16x8*)Bp0;
    u16x8 rb1 = *(const u16x8*)Bp1;

    for (int kk = 0; kk < Kdim; kk += 32) {
        __syncthreads();
        *(u16x8*)&Al[r0 * LTK + c0]        = ra0;
        *(u16x8*)&Al[(r0 + 64) * LTK + c0] = ra1;
        *(u16x8*)&Bl[r0 * LTK + c0]        = rb0;
        *(u16x8*)&Bl[(r0 + 64) * LTK + c0] = rb1;
        __syncthreads();
        if (kk + 32 < Kdim) {
            ra0 = *(const u16x8*)(Ap0 + kk + 32);
            ra1 = *(const u16x8*)(Ap1 + kk + 32);
            rb0 = *(const u16x8*)(Bp0 + kk + 32);
            rb1 = *(const u16x8*)(Bp1 + kk + 32);
        }
        u16x8 af[4], bf[4];
#pragma unroll
        for (int m = 0; m < 4; ++m)
            af[m] = *(const u16x8*)&Al[(wr + m * 16 + fr) * LTK + fk];
#pragma unroll
        for (int n = 0; n < 4; ++n)
            bf[n] = *(const u16x8*)&Bl[(wc + n * 16 + fr) * LTK + fk];
#pragma unroll
        for (int m = 0; m < 4; ++m)
#pragma unroll
            for (int n = 0; n < 4; ++n)
                acc[m][n] = __builtin_amdgcn_mfma_f32_16x16x32_bf16(
                    __builtin_bit_cast(bf16x8, af[m]),
                    __builtin_bit_cast(bf16x8, bf[n]), acc[m][n], 0, 0, 0);
    }

    const int crow = (ln >> 4) * 4;
#pragma unroll
    for (int m = 0; m < 4; ++m)
#pragma unroll
        for (int n = 0; n < 4; ++n) {
            const size_t base = (size_t)(bm + wr + m * 16 + crow) * Ndim
                              + bn + wc + n * 16 + fr;
#pragma unroll
            for (int j = 0; j < 4; ++j)
                C[base + (size_t)j * Ndim] = acc[m][n][j];
        }
}

// ==================== f32 fallback GEMM (ws too small): C = A * B^T ====================

__global__ __launch_bounds__(256)
void g_sgemm_k(const float* __restrict__ A, const float* __restrict__ B,
               float* __restrict__ C, int Mdim, int Ndim, int Kdim)
{
    __shared__ __align__(16) float As[16][132];
    __shared__ __align__(16) float Bs[16][68];
    const int tid = threadIdx.x;
    const int tx = tid & 15, ty = tid >> 4;
    const int bn = blockIdx.x * 64, bm = blockIdx.y * 128;
    const int lrA = tid >> 1, lcA = (tid & 1) << 3;
    const int lrB = tid >> 2, lcB = (tid & 3) << 2;
    const float* Aptr = A + (size_t)(bm + lrA) * Kdim + lcA;
    const float* Bptr = B + (size_t)(bn + lrB) * Kdim + lcB;
    float4 a0 = *(const float4*)(Aptr);
    float4 a1 = *(const float4*)(Aptr + 4);
    float4 b0 = *(const float4*)(Bptr);
    float acc[8][4];
#pragma unroll
    for (int i = 0; i < 8; ++i)
#pragma unroll
        for (int j = 0; j < 4; ++j) acc[i][j] = 0.f;
    for (int kk = 0; kk < Kdim; kk += 16) {
        __syncthreads();
        As[lcA + 0][lrA] = a0.x; As[lcA + 1][lrA] = a0.y;
        As[lcA + 2][lrA] = a0.z; As[lcA + 3][lrA] = a0.w;
        As[lcA + 4][lrA] = a1.x; As[lcA + 5][lrA] = a1.y;
        As[lcA + 6][lrA] = a1.z; As[lcA + 7][lrA] = a1.w;
        Bs[lcB + 0][lrB] = b0.x; Bs[lcB + 1][lrB] = b0.y;
        Bs[lcB + 2][lrB] = b0.z; Bs[lcB + 3][lrB] = b0.w;
        __syncthreads();
        if (kk + 16 < Kdim) {
            a0 = *(const float4*)(Aptr + kk + 16);
            a1 = *(const float4*)(Aptr + kk + 20);
            b0 = *(const float4*)(Bptr + kk + 16);
        }
#pragma unroll
        for (int k = 0; k < 16; ++k) {
            const float4 av0 = *(const float4*)&As[k][ty * 8];
            const float4 av1 = *(const float4*)&As[k][ty * 8 + 4];
            const float4 bv  = *(const float4*)&Bs[k][tx * 4];
            const float avf[8] = {av0.x, av0.y, av0.z, av0.w, av1.x, av1.y, av1.z, av1.w};
            const float bvf[4] = {bv.x, bv.y, bv.z, bv.w};
#pragma unroll
            for (int i = 0; i < 8; ++i)
#pragma unroll
                for (int j = 0; j < 4; ++j) acc[i][j] += avf[i] * bvf[j];
        }
    }
#pragma unroll
    for (int i = 0; i < 8; ++i) {
        const int r = bm + ty * 8 + i;
        float4 v = {acc[i][0], acc[i][1], acc[i][2], acc[i][3]};
        *(float4*)&C[(size_t)r * Ndim + bn + tx * 4] = v;
    }
}

// ==================== merged spectral kernel (H == 2048) ====================
// One block, 512 thr (8 waves). Truncated right-singular subspace of
// A = diag(a)+p q^T per jnp.linalg.pinv rcond, via Haynsworth inertia on
// A^T A = D^2 + W S W^T, W=[a.*p, q], S=[[0,1],[1,c]], c=p.p.
//  Phase A: lambda_max by 8-wave 9-section (6 rounds), float4-vectorized probes.
//  Phase B: near-list (d2 < THETA) + degree-3 Taylor of far-G (err ~2e-9).
//  Phase C: per-eigenvalue PER-LANE 65-section (4 rounds, ballot bracket) —
//           each lane probes its own t; serial broadcast loop over near-list,
//           no cross-lane reduction in the chain.
//  Phase D: batched full eigenvectors + f64 norms -> V.

__device__ __forceinline__ double wsum(double x) {
#pragma unroll
    for (int m = 32; m; m >>= 1) x += __shfl_xor(x, m, 64);
    return x;
}

// inertia from poly-corrected sums
__device__ __forceinline__ int inert(double s11, double s12, double s22,
                                     double dc, double cS)
{
    double b00 = cS - s11, b01 = -1.0 - s12, b11 = -s22;   // -S^{-1} - G
    double det = b00 * b11 - b01 * b01, tr = b00 + b11;
    int neg = (det > 0.0) ? ((tr < 0.0) ? 2 : 0) : 1;
    return (int)(dc + 0.5) + neg - 1;
}

// per-lane serial eval over list (broadcast LDS reads), poly far-correction
__device__ __forceinline__ int lane_evalN(double t, int cnt,
    const float* pl0, const float* pl1, const float* pl2,
    const double* pc, bool poly, double cS,
    double& g11o, double& g12o, double& g22o)
{
    double s11 = 0, s12 = 0, s22 = 0; double dc = 0;
    for (int i = 0; i < cnt; ++i) {
        double den = (double)pl0[i] - t;
        if (fabs(den) < 1e-30) den = (den < 0 ? -1e-30 : 1e-30);
        double inv = 1.0 / den;
        double b1 = (double)pl1[i], b2 = (double)pl2[i];
        s11 += b1 * b1 * inv; s12 += b1 * b2 * inv; s22 += b2 * b2 * inv;
        if ((double)pl0[i] < t) dc += 1.0;
    }
    if (poly) {
        s11 += pc[0] + t * (pc[3] + t * (pc[6] + t * pc[9]));
        s12 += pc[1] + t * (pc[4] + t * (pc[7] + t * pc[10]));
        s22 += pc[2] + t * (pc[5] + t * (pc[8] + t * pc[11]));
    }
    g11o = s11; g12o = s12; g22o = s22;
    return inert(s11, s12, s22, dc, cS);
}

__global__ __launch_bounds__(512)
void spec_k(const float* __restrict__ av, const float* __restrict__ pv,
            const float* __restrict__ qv, double* __restrict__ hdr,
            float* __restrict__ V)
{
    __shared__ float sd2[2048], sw1[2048], sw2[2048];
    __shared__ float nl0[NL_CAP], nl1[NL_CAP], nl2[NL_CAP];
    __shared__ double dsh[192];
    __shared__ int ish[16];

    const int tid = threadIdx.x;
    const int lane = tid & 63, wv = tid >> 6;
    const int j0 = tid * 4;

    float p4[4], d2r[4], w1r[4], w2r[4];
    {
        float4 aa = *(const float4*)&av[j0];
        float4 pp = *(const float4*)&pv[j0];
        float4 qq = *(const float4*)&qv[j0];
        const float a4[4] = {aa.x, aa.y, aa.z, aa.w};
        const float pw[4] = {pp.x, pp.y, pp.z, pp.w};
        const float qw[4] = {qq.x, qq.y, qq.z, qq.w};
#pragma unroll
        for (int e = 0; e < 4; ++e) {
            p4[e] = pw[e];
            d2r[e] = a4[e] * a4[e];
            w1r[e] = a4[e] * pw[e];
            w2r[e] = qw[e];
            sd2[j0 + e] = d2r[e]; sw1[j0 + e] = w1r[e]; sw2[j0 + e] = w2r[e];
        }
    }

    // block reduce: c = p.p, n1 = |w1|^2, n2 = |w2|^2, mx = max d2
    double cS = 0, n1 = 0, n2 = 0, mx = 0;
#pragma unroll
    for (int e = 0; e < 4; ++e) {
        cS += (double)p4[e] * p4[e];
        n1 += (double)w1r[e] * w1r[e];
        n2 += (double)w2r[e] * w2r[e];
        mx = fmax(mx, (double)d2r[e]);
    }
    cS = wsum(cS); n1 = wsum(n1); n2 = wsum(n2);
#pragma unroll
    for (int m = 32; m; m >>= 1) mx = fmax(mx, __shfl_xor(mx, m, 64));
    __syncthreads();
    if (lane == 0) { dsh[wv] = cS; dsh[8 + wv] = n1; dsh[16 + wv] = n2; dsh[24 + wv] = mx; }
    __syncthreads();
    cS = 0; n1 = 0; n2 = 0; mx = 0;
    for (int w = 0; w < 8; ++w) {
        cS += dsh[w]; n1 += dsh[8 + w]; n2 += dsh[16 + w];
        mx = fmax(mx, dsh[24 + w]);
    }
    __syncthreads();

    // ---- Phase A: lambda_max 9-section, vectorized probes ----
    double lo = 0.0;
    double hi = mx + 0.5 * (cS + sqrt(cS * cS + 4.0)) * (n1 + n2) + 1.0;
    for (int r = 0; r < 6; ++r) {
        const double t = lo + (hi - lo) * (double)(wv + 1) / 9.0;
        double s11 = 0, s12 = 0, s22 = 0, dc = 0;
        for (int i4 = lane; i4 < 512; i4 += 64) {
            float4 dd = ((const float4*)sd2)[i4];
            float4 e1 = ((const float4*)sw1)[i4];
            float4 e2 = ((const float4*)sw2)[i4];
            const float df[4] = {dd.x, dd.y, dd.z, dd.w};
            const float f1[4] = {e1.x, e1.y, e1.z, e1.w};
            const float f2[4] = {e2.x, e2.y, e2.z, e2.w};
#pragma unroll
            for (int e = 0; e < 4; ++e) {
                double den = (double)df[e] - t;
                if (fabs(den) < 1e-30) den = (den < 0 ? -1e-30 : 1e-30);
                double inv = 1.0 / den;
                double b1 = (double)f1[e], b2 = (double)f2[e];
                s11 += b1 * b1 * inv; s12 += b1 * b2 * inv; s22 += b2 * b2 * inv;
                if ((double)df[e] < t) dc += 1.0;
            }
        }
        s11 = wsum(s11); s12 = wsum(s12); s22 = wsum(s22); dc = wsum(dc);
        if (lane == 0) ish[wv] = inert(s11, s12, s22, dc, cS);
        __syncthreads();
        double nlo = lo, nhi = hi;
        for (int i = 0; i < 8; ++i) {
            double ti = lo + (hi - lo) * (double)(i + 1) / 9.0;
            if (ish[i] >= 2048) { if (ti < nhi) nhi = ti; }
            else                { if (ti > nlo) nlo = ti; }
        }
        lo = nlo; hi = nhi;
        __syncthreads();
    }
    const double lmax = 0.5 * (lo + hi);
    const double rc = 10.0 * 2048.0 * 1.1920928955078125e-07;
    const double cut2 = rc * rc * lmax;

    // ---- Phase B: near-list + far Taylor coeffs ----
    if (tid == 0) ish[8] = 0;
    __syncthreads();
#pragma unroll
    for (int e = 0; e < 4; ++e) {
        if (d2r[e] < THETA) {
            int pos = atomicAdd(&ish[8], 1);
            if (pos < NL_CAP) { nl0[pos] = d2r[e]; nl1[pos] = w1r[e]; nl2[pos] = w2r[e]; }
        }
    }
    double cf[12];
#pragma unroll
    for (int c = 0; c < 12; ++c) cf[c] = 0;
#pragma unroll
    for (int e = 0; e < 4; ++e) {
        if (d2r[e] >= THETA) {
            double id = 1.0 / (double)d2r[e];
            double b1 = (double)w1r[e], b2 = (double)w2r[e];
            double x11 = b1 * b1, x12 = b1 * b2, x22 = b2 * b2;
            double f = id;
            cf[0] += x11 * f; cf[1]  += x12 * f; cf[2]  += x22 * f; f *= id;
            cf[3] += x11 * f; cf[4]  += x12 * f; cf[5]  += x22 * f; f *= id;
            cf[6] += x11 * f; cf[7]  += x12 * f; cf[8]  += x22 * f; f *= id;
            cf[9] += x11 * f; cf[10] += x12 * f; cf[11] += x22 * f;
        }
    }
#pragma unroll
    for (int c = 0; c < 12; ++c) cf[c] = wsum(cf[c]);
    if (lane == 0) {
        double* dw = &dsh[wv * 12];
#pragma unroll
        for (int c = 0; c < 12; ++c) dw[c] = cf[c];
    }
    __syncthreads();
    if (tid < 12) {
        double s = 0;
        for (int w = 0; w < 8; ++w) s += dsh[w * 12 + tid];
        dsh[96 + tid] = s;
    }
    __syncthreads();

    int cnt = ish[8];
    const float *pl0 = nl0, *pl1 = nl1, *pl2 = nl2;
    bool poly = true;
    if (cnt > NL_CAP) { pl0 = sd2; pl1 = sw1; pl2 = sw2; cnt = 2048; poly = false; }
    const double* pcoef = &dsh[96];

    // m = N(cut2): wave 0, per-lane redundant eval
    double zg1, zg2, zg3;
    if (wv == 0) {
        int N = lane_evalN(cut2, cnt, pl0, pl1, pl2, pcoef, poly, cS, zg1, zg2, zg3);
        if (lane == 0) ish[9] = N;
    }
    __syncthreads();
    int m = ish[9];
    if (m < 0) m = 0;
    if (m > MAXM) m = MAXM;

    // ---- Phase C: per-lane 65-section per eigenvalue (4 rounds) ----
    for (int k = wv; k < m; k += 8) {
        double klo = 0.0, khi = cut2;
        for (int r = 0; r < 4; ++r) {
            const double w = khi - klo;
            const double t = klo + w * (double)(lane + 1) / 65.0;
            int N = lane_evalN(t, cnt, pl0, pl1, pl2, pcoef, poly, cS, zg1, zg2, zg3);
            unsigned long long mask = __ballot(N >= k + 1);
            int j = (mask == 0ull) ? 64 : (__ffsll((unsigned long long)mask) - 1);
            double nk = (j == 64) ? khi : (klo + w * (double)(j + 1) / 65.0);
            klo = klo + w * (double)j / 65.0;   // j==0 -> klo unchanged; j==64 -> t_63
            khi = nk;
        }
        const double lam = 0.5 * (klo + khi);
        double g11, g12, g22;
        lane_evalN(lam, cnt, pl0, pl1, pl2, pcoef, poly, cS, g11, g12, g22);
        // nullvector y of I + G S, z = S y
        const double m00 = 1.0 + g12, m01 = g11 + cS * g12;
        const double m10 = g22,       m11 = 1.0 + g12 + cS * g22;
        double y1, y2;
        if (m00 * m00 + m01 * m01 >= m10 * m10 + m11 * m11) { y1 = m01; y2 = -m00; }
        else                                                { y1 = m11; y2 = -m10; }
        if (lane == 0) {
            dsh[112 + 3 * k]     = lam;
            dsh[112 + 3 * k + 1] = y2;             // z1
            dsh[112 + 3 * k + 2] = y1 + cS * y2;   // z2
        }
    }
    __syncthreads();

    // ---- Phase D: full eigenvectors + f64 norms ----
    for (int k = 0; k < m; ++k) {
        const double lam = dsh[112 + 3 * k];
        const double z1 = dsh[112 + 3 * k + 1], z2 = dsh[112 + 3 * k + 2];
        double vr[4], pn = 0;
#pragma unroll
        for (int e = 0; e < 4; ++e) {
            double den = (double)d2r[e] - lam;
            if (fabs(den) < 1e-30) den = (den < 0 ? -1e-30 : 1e-30);
            vr[e] = ((double)w1r[e] * z1 + (double)w2r[e] * z2) / den;
            pn += vr[e] * vr[e];
        }
        pn = wsum(pn);
        if (lane == 0) dsh[160 + wv] = pn;
        __syncthreads();
        double tot = 0;
        for (int w = 0; w < 8; ++w) tot += dsh[160 + w];
        const double inv = 1.0 / sqrt(tot);
        float4 o = {(float)(vr[0] * inv), (float)(vr[1] * inv),
                    (float)(vr[2] * inv), (float)(vr[3] * inv)};
        *(float4*)&V[(size_t)k * 2048 + j0] = o;
        __syncthreads();
    }

    if (tid == 0) { hdr[0] = lmax; hdr[1] = cut2; hdr[2] = (double)m; hdr[3] = cS; }
}

// ==================== wave-per-row fused series kernel (H == 2048) ====================
// io holds U = x b^T on entry; on exit io = out.
//   o = [sum_{k=0..13} U (M^T)^k/(k+1)!] * d ; o -= P_V o ; o += sum_{k=0..14} h (M^T)^k/k!

__global__ __launch_bounds__(256, 2)
void series_k(float* __restrict__ io, const float* __restrict__ hm,
              const float* __restrict__ qv, const float* __restrict__ pv,
              const float* __restrict__ av, const float* __restrict__ delta,
              const float* __restrict__ V, const double* __restrict__ hdr,
              int useTrunc)
{
    const int lane = threadIdx.x & 63;
    const int row = blockIdx.x * 4 + (threadIdx.x >> 6);
    const float d = delta[0];
    const int m = useTrunc ? (int)hdr[2] : 0;

    float q[32], p[32], a[32], t[32], o[32];
    float* iorow = io + (size_t)row * 2048;
#pragma unroll
    for (int cc = 0; cc < 8; ++cc) {
        const int j = cc * 256 + lane * 4;
        *(float4*)&q[cc * 4] = *(const float4*)&qv[j];
        *(float4*)&p[cc * 4] = *(const float4*)&pv[j];
        *(float4*)&a[cc * 4] = *(const float4*)&av[j];
        *(float4*)&t[cc * 4] = *(const float4*)&iorow[j];
    }
#pragma unroll
    for (int e = 0; e < 32; ++e) o[e] = t[e];

    float cf = 1.f;
    for (int k = 1; k <= 13; ++k) {
        float s = 0.f;
#pragma unroll
        for (int e = 0; e < 32; ++e) s += t[e] * q[e];
#pragma unroll
        for (int msk = 32; msk; msk >>= 1) s += __shfl_xor(s, msk, 64);
        cf /= (float)(k + 1);
        const float ds = d * s;
#pragma unroll
        for (int e = 0; e < 32; ++e) { t[e] = d * a[e] * t[e] + ds * p[e]; o[e] += cf * t[e]; }
    }
#pragma unroll
    for (int e = 0; e < 32; ++e) o[e] *= d;

    for (int k = 0; k < m; ++k) {
        const float* vr = V + (size_t)k * 2048;
        float vk[32];
#pragma unroll
        for (int cc = 0; cc < 8; ++cc)
            *(float4*)&vk[cc * 4] = *(const float4*)&vr[cc * 256 + lane * 4];
        float s = 0.f;
#pragma unroll
        for (int e = 0; e < 32; ++e) s += o[e] * vk[e];
#pragma unroll
        for (int msk = 32; msk; msk >>= 1) s += __shfl_xor(s, msk, 64);
#pragma unroll
        for (int e = 0; e < 32; ++e) o[e] -= s * vk[e];
    }

    const float* hrow = hm + (size_t)row * 2048;
#pragma unroll
    for (int cc = 0; cc < 8; ++cc)
        *(float4*)&t[cc * 4] = *(const float4*)&hrow[cc * 256 + lane * 4];
#pragma unroll
    for (int e = 0; e < 32; ++e) o[e] += t[e];
    cf = 1.f;
    for (int k = 1; k <= 14; ++k) {
        float s = 0.f;
#pragma unroll
        for (int e = 0; e < 32; ++e) s += t[e] * q[e];
#pragma unroll
        for (int msk = 32; msk; msk >>= 1) s += __shfl_xor(s, msk, 64);
        cf /= (float)k;
        const float ds = d * s;
#pragma unroll
        for (int e = 0; e < 32; ++e) { t[e] = d * a[e] * t[e] + ds * p[e]; o[e] += cf * t[e]; }
    }
#pragma unroll
    for (int cc = 0; cc < 8; ++cc)
        *(float4*)&iorow[cc * 256 + lane * 4] = *(const float4*)&o[cc * 4];
}

// ==================== host orchestration ====================
// out = h expm(dA)^T + d*(x b^T) phi1(dA^T) (I - P_V);  P_V = truncated
// right-singular subspace of A per jnp.linalg.pinv rcond (exact identity).

extern "C" void kernel_launch(void* const* d_in, const int* in_sizes, int n_in,
                              void* d_out, int out_size, void* d_ws, size_t ws_size,
                              hipStream_t stream)
{
    const float* hmat  = (const float*)d_in[0];
    const float* xmat  = (const float*)d_in[1];
    const float* adiag = (const float*)d_in[2];
    const float* pvec  = (const float*)d_in[3];
    const float* qvec  = (const float*)d_in[4];
    const float* bmat  = (const float*)d_in[5];
    const float* delta = (const float*)d_in[6];
    float* out = (float*)d_out;

    const int H  = in_sizes[2];
    const int Bb = in_sizes[0] / H;
    const size_t SZ = (size_t)Bb * H;
    const size_t HH = (size_t)H * H;

    double* hdr = (double*)d_ws;
    float* V = (float*)(hdr + 8);
    u16* xb = (u16*)(V + (size_t)MAXM * H);
    u16* bb = xb + SZ;

    const size_t needSpec = 64 + (size_t)MAXM * H * sizeof(float);
    const size_t needFull = needSpec + (SZ + HH) * sizeof(u16);
    const bool doTrunc = (H == 2048) && (ws_size >= needSpec);
    const bool doBf16  = (ws_size >= needFull);

    dim3 blk256(256);

    if (doTrunc)
        spec_k<<<1, 512, 0, stream>>>(adiag, pvec, qvec, hdr, V);

    // U = x b^T -> d_out
    if (doBf16) {
        const long nmax = (long)(SZ > HH ? SZ : HH);
        const int cg = (int)((nmax / 4 + 255) / 256);
        conv_k<<<cg, blk256, 0, stream>>>(xmat, bmat, xb, bb, (long)SZ, (long)HH);
        dim3 gg(H / 128, Bb / 128);
        bgemm_k<<<gg, blk256, 0, stream>>>(xb, bb, out, Bb, H, H);
    } else {
        dim3 gg(H / 64, Bb / 128);
        g_sgemm_k<<<gg, blk256, 0, stream>>>(xmat, bmat, out, Bb, H, H);
    }

    // fused series + projection, in-place on d_out
    series_k<<<Bb / 4, blk256, 0, stream>>>(out, hmat, qvec, pvec, adiag, delta,
                                            V, hdr, doTrunc ? 1 : 0);
}

// Round 8
// 126.306 us; speedup vs baseline: 1.4144x; 1.4144x over previous
//
#include <hip/hip_runtime.h>

#define MAXM 16
#define NL_CAP 256
#define THETA 0.1f
#define LTK 72
#define SMEM_BYTES 36864

typedef unsigned short u16;
typedef u16 u16x8 __attribute__((ext_vector_type(8)));
typedef u16 u16x4 __attribute__((ext_vector_type(4)));
typedef __bf16 bf16x8 __attribute__((ext_vector_type(8)));
typedef float f32x4 __attribute__((ext_vector_type(4)));

// ==================== f32 -> bf16 (RNE) ====================

__device__ __forceinline__ u16 f2bf(float f) {
    unsigned u = __float_as_uint(f);
    return (u16)((u + 0x7fffu + ((u >> 16) & 1u)) >> 16);
}

__global__ __launch_bounds__(256)
void conv_k(const float* __restrict__ x, const float* __restrict__ b,
            u16* __restrict__ xb, u16* __restrict__ bb, long nx, long nb)
{
    long i = ((long)blockIdx.x * 256 + threadIdx.x) * 4;
    if (i < nx) {
        float4 v = *(const float4*)&x[i];
        u16x4 o = {f2bf(v.x), f2bf(v.y), f2bf(v.z), f2bf(v.w)};
        *(u16x4*)&xb[i] = o;
    }
    if (i < nb) {
        float4 v = *(const float4*)&b[i];
        u16x4 o = {f2bf(v.x), f2bf(v.y), f2bf(v.z), f2bf(v.w)};
        *(u16x4*)&bb[i] = o;
    }
}

// ==================== bf16 MFMA GEMM tile (device fn) ====================
// C[128x128] tile at (bx,by): A [M,K] bf16, B [N,K] bf16, C f32, K%32==0.

__device__ __forceinline__ void gemm_tile(u16* Al, u16* Bl, int tid, int bx, int by,
                                          const u16* __restrict__ A,
                                          const u16* __restrict__ B,
                                          float* __restrict__ C,
                                          int Ndim, int Kdim)
{
    const int bm = by * 128, bn = bx * 128;
    const int wv = tid >> 6, ln = tid & 63;
    const int wr = (wv >> 1) * 64, wc = (wv & 1) * 64;
    const int fr = ln & 15, fk = (ln >> 4) * 8;

    const int r0 = tid >> 2, c0 = (tid & 3) * 8;
    const u16* Ap0 = A + (size_t)(bm + r0) * Kdim + c0;
    const u16* Ap1 = Ap0 + (size_t)64 * Kdim;
    const u16* Bp0 = B + (size_t)(bn + r0) * Kdim + c0;
    const u16* Bp1 = Bp0 + (size_t)64 * Kdim;

    f32x4 acc[4][4];
#pragma unroll
    for (int m = 0; m < 4; ++m)
#pragma unroll
        for (int n = 0; n < 4; ++n) acc[m][n] = (f32x4)0.f;

    u16x8 ra0 = *(const u16x8*)Ap0;
    u16x8 ra1 = *(const u16x8*)Ap1;
    u16x8 rb0 = *(const u16x8*)Bp0;
    u16x8 rb1 = *(const u16x8*)Bp1;

    for (int kk = 0; kk < Kdim; kk += 32) {
        __syncthreads();
        *(u16x8*)&Al[r0 * LTK + c0]        = ra0;
        *(u16x8*)&Al[(r0 + 64) * LTK + c0] = ra1;
        *(u16x8*)&Bl[r0 * LTK + c0]        = rb0;
        *(u16x8*)&Bl[(r0 + 64) * LTK + c0] = rb1;
        __syncthreads();
        if (kk + 32 < Kdim) {
            ra0 = *(const u16x8*)(Ap0 + kk + 32);
            ra1 = *(const u16x8*)(Ap1 + kk + 32);
            rb0 = *(const u16x8*)(Bp0 + kk + 32);
            rb1 = *(const u16x8*)(Bp1 + kk + 32);
        }
        u16x8 af[4], bf[4];
#pragma unroll
        for (int m = 0; m < 4; ++m)
            af[m] = *(const u16x8*)&Al[(wr + m * 16 + fr) * LTK + fk];
#pragma unroll
        for (int n = 0; n < 4; ++n)
            bf[n] = *(const u16x8*)&Bl[(wc + n * 16 + fr) * LTK + fk];
#pragma unroll
        for (int m = 0; m < 4; ++m)
#pragma unroll
            for (int n = 0; n < 4; ++n)
                acc[m][n] = __builtin_amdgcn_mfma_f32_16x16x32_bf16(
                    __builtin_bit_cast(bf16x8, af[m]),
                    __builtin_bit_cast(bf16x8, bf[n]), acc[m][n], 0, 0, 0);
    }

    const int crow = (ln >> 4) * 4;
#pragma unroll
    for (int m = 0; m < 4; ++m)
#pragma unroll
        for (int n = 0; n < 4; ++n) {
            const size_t base = (size_t)(bm + wr + m * 16 + crow) * Ndim
                              + bn + wc + n * 16 + fr;
#pragma unroll
            for (int j = 0; j < 4; ++j)
                C[base + (size_t)j * Ndim] = acc[m][n][j];
        }
}

__global__ __launch_bounds__(256)
void bgemm_k(const u16* __restrict__ A, const u16* __restrict__ B,
             float* __restrict__ C, int Ndim, int Kdim)
{
    __shared__ __align__(16) unsigned char smem[SMEM_BYTES];
    gemm_tile((u16*)smem, (u16*)smem + 128 * LTK, threadIdx.x,
              blockIdx.x, blockIdx.y, A, B, C, Ndim, Kdim);
}

// ==================== f32 fallback GEMM (ws too small): C = A * B^T ====================

__global__ __launch_bounds__(256)
void g_sgemm_k(const float* __restrict__ A, const float* __restrict__ B,
               float* __restrict__ C, int Mdim, int Ndim, int Kdim)
{
    __shared__ __align__(16) float As[16][132];
    __shared__ __align__(16) float Bs[16][68];
    const int tid = threadIdx.x;
    const int tx = tid & 15, ty = tid >> 4;
    const int bn = blockIdx.x * 64, bm = blockIdx.y * 128;
    const int lrA = tid >> 1, lcA = (tid & 1) << 3;
    const int lrB = tid >> 2, lcB = (tid & 3) << 2;
    const float* Aptr = A + (size_t)(bm + lrA) * Kdim + lcA;
    const float* Bptr = B + (size_t)(bn + lrB) * Kdim + lcB;
    float4 a0 = *(const float4*)(Aptr);
    float4 a1 = *(const float4*)(Aptr + 4);
    float4 b0 = *(const float4*)(Bptr);
    float acc[8][4];
#pragma unroll
    for (int i = 0; i < 8; ++i)
#pragma unroll
        for (int j = 0; j < 4; ++j) acc[i][j] = 0.f;
    for (int kk = 0; kk < Kdim; kk += 16) {
        __syncthreads();
        As[lcA + 0][lrA] = a0.x; As[lcA + 1][lrA] = a0.y;
        As[lcA + 2][lrA] = a0.z; As[lcA + 3][lrA] = a0.w;
        As[lcA + 4][lrA] = a1.x; As[lcA + 5][lrA] = a1.y;
        As[lcA + 6][lrA] = a1.z; As[lcA + 7][lrA] = a1.w;
        Bs[lcB + 0][lrB] = b0.x; Bs[lcB + 1][lrB] = b0.y;
        Bs[lcB + 2][lrB] = b0.z; Bs[lcB + 3][lrB] = b0.w;
        __syncthreads();
        if (kk + 16 < Kdim) {
            a0 = *(const float4*)(Aptr + kk + 16);
            a1 = *(const float4*)(Aptr + kk + 20);
            b0 = *(const float4*)(Bptr + kk + 16);
        }
#pragma unroll
        for (int k = 0; k < 16; ++k) {
            const float4 av0 = *(const float4*)&As[k][ty * 8];
            const float4 av1 = *(const float4*)&As[k][ty * 8 + 4];
            const float4 bv  = *(const float4*)&Bs[k][tx * 4];
            const float avf[8] = {av0.x, av0.y, av0.z, av0.w, av1.x, av1.y, av1.z, av1.w};
            const float bvf[4] = {bv.x, bv.y, bv.z, bv.w};
#pragma unroll
            for (int i = 0; i < 8; ++i)
#pragma unroll
                for (int j = 0; j < 4; ++j) acc[i][j] += avf[i] * bvf[j];
        }
    }
#pragma unroll
    for (int i = 0; i < 8; ++i) {
        const int r = bm + ty * 8 + i;
        float4 v = {acc[i][0], acc[i][1], acc[i][2], acc[i][3]};
        *(float4*)&C[(size_t)r * Ndim + bn + tx * 4] = v;
    }
}

// ==================== spectral solve (device fn, 256 thr, H == 2048) ====================
// Truncated right-singular subspace of A = diag(a)+p q^T per jnp.linalg.pinv
// rcond, via Haynsworth inertia on A^T A = D^2 + W S W^T, W=[a.*p, q],
// S=[[0,1],[1,c]], c=p.p.
//  A: lambda_max by 4-wave 5-section (8 rounds, rel err 3.3e-6).
//  B: deterministic near-list (d2<THETA) scan-compaction + deg-3 far Taylor.
//  C: per-lane 65-section (4 rounds) per eigenvalue, float4-vectorized evals.
//  D: batched full eigenvectors + f64 norms -> V.

__device__ __forceinline__ double wsum(double x) {
#pragma unroll
    for (int m = 32; m; m >>= 1) x += __shfl_xor(x, m, 64);
    return x;
}

__device__ __forceinline__ int inert(double s11, double s12, double s22,
                                     double dc, double cS)
{
    double b00 = cS - s11, b01 = -1.0 - s12, b11 = -s22;   // -S^{-1} - G
    double det = b00 * b11 - b01 * b01, tr = b00 + b11;
    int neg = (det > 0.0) ? ((tr < 0.0) ? 2 : 0) : 1;
    return (int)(dc + 0.5) + neg - 1;
}

__device__ __forceinline__ int lane_evalN4(double t, int n4,
    const float4* l0, const float4* l1, const float4* l2,
    const double* pc, bool poly, double cS,
    double& g11o, double& g12o, double& g22o)
{
    double s11 = 0, s12 = 0, s22 = 0, dc = 0;
#pragma unroll 2
    for (int i = 0; i < n4; ++i) {
        const float4 d4 = l0[i], x4 = l1[i], y4 = l2[i];
        const float dd[4] = {d4.x, d4.y, d4.z, d4.w};
        const float xx[4] = {x4.x, x4.y, x4.z, x4.w};
        const float yy[4] = {y4.x, y4.y, y4.z, y4.w};
#pragma unroll
        for (int e = 0; e < 4; ++e) {
            double den = (double)dd[e] - t;
            if (fabs(den) < 1e-30) den = (den < 0 ? -1e-30 : 1e-30);
            double inv = 1.0 / den;
            double b1 = (double)xx[e], b2 = (double)yy[e];
            s11 += b1 * b1 * inv; s12 += b1 * b2 * inv; s22 += b2 * b2 * inv;
            if ((double)dd[e] < t) dc += 1.0;
        }
    }
    if (poly) {
        s11 += pc[0] + t * (pc[3] + t * (pc[6] + t * pc[9]));
        s12 += pc[1] + t * (pc[4] + t * (pc[7] + t * pc[10]));
        s22 += pc[2] + t * (pc[5] + t * (pc[8] + t * pc[11]));
    }
    g11o = s11; g12o = s12; g22o = s22;
    return inert(s11, s12, s22, dc, cS);
}

__device__ void spec256(unsigned char* smem, int tid,
                        const float* __restrict__ av, const float* __restrict__ pv,
                        const float* __restrict__ qv, double* __restrict__ hdr,
                        float* __restrict__ V)
{
    float* sd2 = (float*)smem;          // 2048
    float* sw1 = sd2 + 2048;
    float* sw2 = sw1 + 2048;
    float* nl0 = sw2 + 2048;            // NL_CAP each
    float* nl1 = nl0 + NL_CAP;
    float* nl2 = nl1 + NL_CAP;
    double* dsh = (double*)(nl2 + NL_CAP);   // 192 doubles
    int* ish = (int*)(dsh + 192);            // 16 ints

    const int lane = tid & 63, wv = tid >> 6;
    const int j0 = tid * 8;

    float d2r[8], w1r[8], w2r[8];
    double cS = 0, n1 = 0, n2 = 0, mx = 0;
#pragma unroll
    for (int h = 0; h < 2; ++h) {
        float4 aa = *(const float4*)&av[j0 + h * 4];
        float4 pp = *(const float4*)&pv[j0 + h * 4];
        float4 qq = *(const float4*)&qv[j0 + h * 4];
        const float a4[4] = {aa.x, aa.y, aa.z, aa.w};
        const float p4[4] = {pp.x, pp.y, pp.z, pp.w};
        const float q4[4] = {qq.x, qq.y, qq.z, qq.w};
#pragma unroll
        for (int e = 0; e < 4; ++e) {
            const int ix = h * 4 + e;
            d2r[ix] = a4[e] * a4[e];
            w1r[ix] = a4[e] * p4[e];
            w2r[ix] = q4[e];
            sd2[j0 + ix] = d2r[ix]; sw1[j0 + ix] = w1r[ix]; sw2[j0 + ix] = w2r[ix];
            cS += (double)p4[e] * p4[e];
            n1 += (double)w1r[ix] * w1r[ix];
            n2 += (double)w2r[ix] * w2r[ix];
            mx = fmax(mx, (double)d2r[ix]);
        }
    }
    cS = wsum(cS); n1 = wsum(n1); n2 = wsum(n2);
#pragma unroll
    for (int m_ = 32; m_; m_ >>= 1) mx = fmax(mx, __shfl_xor(mx, m_, 64));
    __syncthreads();
    if (lane == 0) { dsh[wv] = cS; dsh[4 + wv] = n1; dsh[8 + wv] = n2; dsh[12 + wv] = mx; }
    __syncthreads();
    cS = 0; n1 = 0; n2 = 0; mx = 0;
    for (int w = 0; w < 4; ++w) {
        cS += dsh[w]; n1 += dsh[4 + w]; n2 += dsh[8 + w];
        mx = fmax(mx, dsh[12 + w]);
    }
    __syncthreads();

    // ---- Phase A: lambda_max 5-section x 8 rounds ----
    double lo = 0.0;
    double hi = mx + 0.5 * (cS + sqrt(cS * cS + 4.0)) * (n1 + n2) + 1.0;
    for (int r = 0; r < 8; ++r) {
        const double t = lo + (hi - lo) * (double)(wv + 1) / 5.0;
        double s11 = 0, s12 = 0, s22 = 0, dc = 0;
        for (int i4 = lane; i4 < 512; i4 += 64) {
            const float4 dd = ((const float4*)sd2)[i4];
            const float4 e1 = ((const float4*)sw1)[i4];
            const float4 e2 = ((const float4*)sw2)[i4];
            const float df[4] = {dd.x, dd.y, dd.z, dd.w};
            const float f1[4] = {e1.x, e1.y, e1.z, e1.w};
            const float f2[4] = {e2.x, e2.y, e2.z, e2.w};
#pragma unroll
            for (int e = 0; e < 4; ++e) {
                double den = (double)df[e] - t;
                if (fabs(den) < 1e-30) den = (den < 0 ? -1e-30 : 1e-30);
                double inv = 1.0 / den;
                double b1 = (double)f1[e], b2 = (double)f2[e];
                s11 += b1 * b1 * inv; s12 += b1 * b2 * inv; s22 += b2 * b2 * inv;
                if ((double)df[e] < t) dc += 1.0;
            }
        }
        s11 = wsum(s11); s12 = wsum(s12); s22 = wsum(s22); dc = wsum(dc);
        if (lane == 0) ish[wv] = inert(s11, s12, s22, dc, cS);
        __syncthreads();
        double nlo = lo, nhi = hi;
        for (int i = 0; i < 4; ++i) {
            double ti = lo + (hi - lo) * (double)(i + 1) / 5.0;
            if (ish[i] >= 2048) { if (ti < nhi) nhi = ti; }
            else                { if (ti > nlo) nlo = ti; }
        }
        lo = nlo; hi = nhi;
        __syncthreads();
    }
    const double lmax = 0.5 * (lo + hi);
    const double rc = 10.0 * 2048.0 * 1.1920928955078125e-07;
    const double cut2 = rc * rc * lmax;

    // ---- Phase B: deterministic near-list compaction + far Taylor coeffs ----
    int flags = 0, lc = 0;
#pragma unroll
    for (int e = 0; e < 8; ++e)
        if (d2r[e] < THETA) { flags |= (1 << e); ++lc; }
    int sc = lc;
#pragma unroll
    for (int off = 1; off < 64; off <<= 1) {
        int y = __shfl_up(sc, off, 64);
        if (lane >= off) sc += y;
    }
    const int wtot = __shfl(sc, 63, 64);
    const int excl = sc - lc;
    if (lane == 0) ish[4 + wv] = wtot;
    __syncthreads();
    int base = excl;
    for (int w = 0; w < wv; ++w) base += ish[4 + w];
    int cnt = 0;
    for (int w = 0; w < 4; ++w) cnt += ish[4 + w];
    {
        int pos = base;
#pragma unroll
        for (int e = 0; e < 8; ++e) {
            if (flags & (1 << e)) {
                if (pos < NL_CAP) { nl0[pos] = d2r[e]; nl1[pos] = w1r[e]; nl2[pos] = w2r[e]; }
                ++pos;
            }
        }
    }
    const int cntPad = (cnt + 7) & ~7;
    if (tid == 0) {
        for (int i = cnt; i < cntPad && i < NL_CAP; ++i) {
            nl0[i] = 1e30f; nl1[i] = 0.f; nl2[i] = 0.f;   // exact no-op entries
        }
        ish[8] = cnt; ish[10] = cntPad >> 2;
    }

    double cf[12];
#pragma unroll
    for (int c = 0; c < 12; ++c) cf[c] = 0;
#pragma unroll
    for (int e = 0; e < 8; ++e) {
        if (d2r[e] >= THETA) {
            double id = 1.0 / (double)d2r[e];
            double b1 = (double)w1r[e], b2 = (double)w2r[e];
            double x11 = b1 * b1, x12 = b1 * b2, x22 = b2 * b2;
            double f = id;
            cf[0] += x11 * f; cf[1]  += x12 * f; cf[2]  += x22 * f; f *= id;
            cf[3] += x11 * f; cf[4]  += x12 * f; cf[5]  += x22 * f; f *= id;
            cf[6] += x11 * f; cf[7]  += x12 * f; cf[8]  += x22 * f; f *= id;
            cf[9] += x11 * f; cf[10] += x12 * f; cf[11] += x22 * f;
        }
    }
#pragma unroll
    for (int c = 0; c < 12; ++c) cf[c] = wsum(cf[c]);
    if (lane == 0) {
        double* dw = &dsh[16 + wv * 12];
#pragma unroll
        for (int c = 0; c < 12; ++c) dw[c] = cf[c];
    }
    __syncthreads();
    if (tid < 12) {
        double s = 0;
        for (int w = 0; w < 4; ++w) s += dsh[16 + w * 12 + tid];
        dsh[96 + tid] = s;
    }
    __syncthreads();

    cnt = ish[8];
    const bool nearOK = (cnt <= NL_CAP - 8);
    const float4* l0 = nearOK ? (const float4*)nl0 : (const float4*)sd2;
    const float4* l1 = nearOK ? (const float4*)nl1 : (const float4*)sw1;
    const float4* l2 = nearOK ? (const float4*)nl2 : (const float4*)sw2;
    const int n4 = nearOK ? ish[10] : 512;
    const bool poly = nearOK;
    const double* pcoef = &dsh[96];

    double zg1, zg2, zg3;
    if (wv == 0) {
        int N = lane_evalN4(cut2, n4, l0, l1, l2, pcoef, poly, cS, zg1, zg2, zg3);
        if (lane == 0) ish[9] = N;
    }
    __syncthreads();
    int m = ish[9];
    if (m < 0) m = 0;
    if (m > MAXM) m = MAXM;

    // ---- Phase C: per-lane 65-section, eigenvalues striped over 4 waves ----
    for (int k = wv; k < m; k += 4) {
        double klo = 0.0, khi = cut2;
        for (int r = 0; r < 4; ++r) {
            const double w = khi - klo;
            const double t = klo + w * (double)(lane + 1) / 65.0;
            int N = lane_evalN4(t, n4, l0, l1, l2, pcoef, poly, cS, zg1, zg2, zg3);
            unsigned long long mask = __ballot(N >= k + 1);
            int j = (mask == 0ull) ? 64 : (__ffsll(mask) - 1);
            double nk = (j == 64) ? khi : (klo + w * (double)(j + 1) / 65.0);
            klo = klo + w * (double)j / 65.0;
            khi = nk;
        }
        const double lam = 0.5 * (klo + khi);
        double g11, g12, g22;
        lane_evalN4(lam, n4, l0, l1, l2, pcoef, poly, cS, g11, g12, g22);
        const double m00 = 1.0 + g12, m01 = g11 + cS * g12;
        const double m10 = g22,       m11 = 1.0 + g12 + cS * g22;
        double y1, y2;
        if (m00 * m00 + m01 * m01 >= m10 * m10 + m11 * m11) { y1 = m01; y2 = -m00; }
        else                                                { y1 = m11; y2 = -m10; }
        if (lane == 0) {
            dsh[112 + 3 * k]     = lam;
            dsh[112 + 3 * k + 1] = y2;             // z1
            dsh[112 + 3 * k + 2] = y1 + cS * y2;   // z2
        }
    }
    __syncthreads();

    // ---- Phase D: full eigenvectors + f64 norms ----
    for (int k = 0; k < m; ++k) {
        const double lam = dsh[112 + 3 * k];
        const double z1 = dsh[112 + 3 * k + 1], z2 = dsh[112 + 3 * k + 2];
        double vr[8], pn = 0;
#pragma unroll
        for (int e = 0; e < 8; ++e) {
            double den = (double)d2r[e] - lam;
            if (fabs(den) < 1e-30) den = (den < 0 ? -1e-30 : 1e-30);
            vr[e] = ((double)w1r[e] * z1 + (double)w2r[e] * z2) / den;
            pn += vr[e] * vr[e];
        }
        pn = wsum(pn);
        if (lane == 0) dsh[160 + wv] = pn;
        __syncthreads();
        double tot = 0;
        for (int w = 0; w < 4; ++w) tot += dsh[160 + w];
        const double inv = 1.0 / sqrt(tot);
        float o0[8];
#pragma unroll
        for (int e = 0; e < 8; ++e) o0[e] = (float)(vr[e] * inv);
        *(float4*)&V[(size_t)k * 2048 + j0]     = *(float4*)&o0[0];
        *(float4*)&V[(size_t)k * 2048 + j0 + 4] = *(float4*)&o0[4];
        __syncthreads();
    }

    if (tid == 0) { hdr[0] = lmax; hdr[1] = cut2; hdr[2] = (double)m; hdr[3] = cS; }
}

// ==================== fat kernel: block 0 = spec, blocks 1..ntiles = GEMM ====================

__global__ __launch_bounds__(256)
void fat_k(const u16* __restrict__ A, const u16* __restrict__ B,
           float* __restrict__ C, int Ndim, int Kdim, int ntiles, int nbx,
           const float* __restrict__ av, const float* __restrict__ pv,
           const float* __restrict__ qv, double* __restrict__ hdr,
           float* __restrict__ V)
{
    __shared__ __align__(16) unsigned char smem[SMEM_BYTES];
    const int bid = blockIdx.x;
    if (bid == 0) {
        spec256(smem, threadIdx.x, av, pv, qv, hdr, V);
        return;
    }
    if (bid - 1 >= ntiles) return;
    const int t = bid - 1;
    gemm_tile((u16*)smem, (u16*)smem + 128 * LTK, threadIdx.x,
              t % nbx, t / nbx, A, B, C, Ndim, Kdim);
}

// ==================== wave-per-row fused series kernel (H == 2048) ====================
// io holds U = x b^T on entry; on exit io = out.
//   o = [sum_{k=0..13} U (M^T)^k/(k+1)!] * d ; o -= P_V o ; o += sum_{k=0..14} h (M^T)^k/k!

__global__ __launch_bounds__(256, 2)
void series_k(float* __restrict__ io, const float* __restrict__ hm,
              const float* __restrict__ qv, const float* __restrict__ pv,
              const float* __restrict__ av, const float* __restrict__ delta,
              const float* __restrict__ V, const double* __restrict__ hdr,
              int useTrunc)
{
    const int lane = threadIdx.x & 63;
    const int row = blockIdx.x * 4 + (threadIdx.x >> 6);
    const float d = delta[0];
    const int m = useTrunc ? (int)hdr[2] : 0;

    float q[32], p[32], a[32], t[32], o[32];
    float* iorow = io + (size_t)row * 2048;
#pragma unroll
    for (int cc = 0; cc < 8; ++cc) {
        const int j = cc * 256 + lane * 4;
        *(float4*)&q[cc * 4] = *(const float4*)&qv[j];
        *(float4*)&p[cc * 4] = *(const float4*)&pv[j];
        *(float4*)&a[cc * 4] = *(const float4*)&av[j];
        *(float4*)&t[cc * 4] = *(const float4*)&iorow[j];
    }
#pragma unroll
    for (int e = 0; e < 32; ++e) o[e] = t[e];

    float cf = 1.f;
    for (int k = 1; k <= 13; ++k) {
        float s = 0.f;
#pragma unroll
        for (int e = 0; e < 32; ++e) s += t[e] * q[e];
#pragma unroll
        for (int msk = 32; msk; msk >>= 1) s += __shfl_xor(s, msk, 64);
        cf /= (float)(k + 1);
        const float ds = d * s;
#pragma unroll
        for (int e = 0; e < 32; ++e) { t[e] = d * a[e] * t[e] + ds * p[e]; o[e] += cf * t[e]; }
    }
#pragma unroll
    for (int e = 0; e < 32; ++e) o[e] *= d;

    for (int k = 0; k < m; ++k) {
        const float* vr = V + (size_t)k * 2048;
        float vk[32];
#pragma unroll
        for (int cc = 0; cc < 8; ++cc)
            *(float4*)&vk[cc * 4] = *(const float4*)&vr[cc * 256 + lane * 4];
        float s = 0.f;
#pragma unroll
        for (int e = 0; e < 32; ++e) s += o[e] * vk[e];
#pragma unroll
        for (int msk = 32; msk; msk >>= 1) s += __shfl_xor(s, msk, 64);
#pragma unroll
        for (int e = 0; e < 32; ++e) o[e] -= s * vk[e];
    }

    const float* hrow = hm + (size_t)row * 2048;
#pragma unroll
    for (int cc = 0; cc < 8; ++cc)
        *(float4*)&t[cc * 4] = *(const float4*)&hrow[cc * 256 + lane * 4];
#pragma unroll
    for (int e = 0; e < 32; ++e) o[e] += t[e];
    cf = 1.f;
    for (int k = 1; k <= 14; ++k) {
        float s = 0.f;
#pragma unroll
        for (int e = 0; e < 32; ++e) s += t[e] * q[e];
#pragma unroll
        for (int msk = 32; msk; msk >>= 1) s += __shfl_xor(s, msk, 64);
        cf /= (float)k;
        const float ds = d * s;
#pragma unroll
        for (int e = 0; e < 32; ++e) { t[e] = d * a[e] * t[e] + ds * p[e]; o[e] += cf * t[e]; }
    }
#pragma unroll
    for (int cc = 0; cc < 8; ++cc)
        *(float4*)&iorow[cc * 256 + lane * 4] = *(const float4*)&o[cc * 4];
}

// ==================== host orchestration ====================
// out = h expm(dA)^T + d*(x b^T) phi1(dA^T) (I - P_V);  P_V = truncated
// right-singular subspace of A per jnp.linalg.pinv rcond (exact identity).
// conv -> fat(spec block 0 || 256 GEMM tiles) -> series: spec cost hides
// under the GEMM instead of serializing on one CU.

extern "C" void kernel_launch(void* const* d_in, const int* in_sizes, int n_in,
                              void* d_out, int out_size, void* d_ws, size_t ws_size,
                              hipStream_t stream)
{
    const float* hmat  = (const float*)d_in[0];
    const float* xmat  = (const float*)d_in[1];
    const float* adiag = (const float*)d_in[2];
    const float* pvec  = (const float*)d_in[3];
    const float* qvec  = (const float*)d_in[4];
    const float* bmat  = (const float*)d_in[5];
    const float* delta = (const float*)d_in[6];
    float* out = (float*)d_out;

    const int H  = in_sizes[2];
    const int Bb = in_sizes[0] / H;
    const size_t SZ = (size_t)Bb * H;
    const size_t HH = (size_t)H * H;

    double* hdr = (double*)d_ws;
    float* V = (float*)(hdr + 8);
    u16* xb = (u16*)(V + (size_t)MAXM * H);
    u16* bb = xb + SZ;

    const size_t needSpec = 64 + (size_t)MAXM * H * sizeof(float);
    const size_t needFull = needSpec + (SZ + HH) * sizeof(u16);
    const bool doTrunc = (H == 2048) && (ws_size >= needSpec);
    const bool doBf16  = (ws_size >= needFull) && (H % 128 == 0) && (Bb % 128 == 0);

    dim3 blk256(256);
    const int nbx = H / 128;
    const int ntiles = nbx * (Bb / 128);

    if (doBf16) {
        const long nmax = (long)(SZ > HH ? SZ : HH);
        const int cg = (int)((nmax / 4 + 255) / 256);
        conv_k<<<cg, blk256, 0, stream>>>(xmat, bmat, xb, bb, (long)SZ, (long)HH);
        if (doTrunc) {
            fat_k<<<1 + ntiles, blk256, 0, stream>>>(xb, bb, out, H, H, ntiles, nbx,
                                                     adiag, pvec, qvec, hdr, V);
        } else {
            dim3 gg(nbx, Bb / 128);
            bgemm_k<<<gg, blk256, 0, stream>>>(xb, bb, out, H, H);
        }
    } else {
        if (doTrunc)
            fat_k<<<1, blk256, 0, stream>>>(nullptr, nullptr, out, H, H, 0, 1,
                                            adiag, pvec, qvec, hdr, V);
        dim3 gg(H / 64, Bb / 128);
        g_sgemm_k<<<gg, blk256, 0, stream>>>(xmat, bmat, out, Bb, H, H);
    }

    // fused series + projection, in-place on d_out
    series_k<<<Bb / 4, blk256, 0, stream>>>(out, hmat, qvec, pvec, adiag, delta,
                                            V, hdr, doTrunc ? 1 : 0);
}

// Round 9
// 116.295 us; speedup vs baseline: 1.5362x; 1.0861x over previous
//
#include <hip/hip_runtime.h>

#define MAXM 16
#define NL_CAP 256
#define THETA 0.1f
#define SMEM_BYTES 36864

typedef unsigned short u16;
typedef u16 u16x8 __attribute__((ext_vector_type(8)));
typedef u16 u16x4 __attribute__((ext_vector_type(4)));
typedef __bf16 bf16x8 __attribute__((ext_vector_type(8)));
typedef float f32x4 __attribute__((ext_vector_type(4)));

// ==================== f32 -> bf16 (RNE) ====================

__device__ __forceinline__ u16 f2bf(float f) {
    unsigned u = __float_as_uint(f);
    return (u16)((u + 0x7fffu + ((u >> 16) & 1u)) >> 16);
}

__global__ __launch_bounds__(256)
void conv_k(const float* __restrict__ x, const float* __restrict__ b,
            u16* __restrict__ xb, u16* __restrict__ bb, long nx, long nb)
{
    long i = ((long)blockIdx.x * 256 + threadIdx.x) * 4;
    if (i < nx) {
        float4 v = *(const float4*)&x[i];
        u16x4 o = {f2bf(v.x), f2bf(v.y), f2bf(v.z), f2bf(v.w)};
        *(u16x4*)&xb[i] = o;
    }
    if (i < nb) {
        float4 v = *(const float4*)&b[i];
        u16x4 o = {f2bf(v.x), f2bf(v.y), f2bf(v.z), f2bf(v.w)};
        *(u16x4*)&bb[i] = o;
    }
}

// ==================== fast f64 reciprocal: v_rcp_f32 + 1 f64 Newton ====================
// rel err ~1e-14; requires |den| >= ~1e-25 (f32-normal range).

__device__ __forceinline__ double frcp(double den) {
    double r = (double)__builtin_amdgcn_rcpf((float)den);
    return fma(r, fma(-den, r, 1.0), r);
}

// ==================== bf16 MFMA GEMM tile (device fn) ====================
// C[128x128] tile at (bx,by): A [M,K] bf16, B [N,K] bf16, C f32, K%32==0.
// m97 recipe: global_load_lds dwordx4 staging into LINEAR [128][32] u16 LDS,
// 2 barriers per K-step (compiler drains vmcnt before s_barrier).

__device__ __forceinline__ void gload_lds16(const void* g, void* l) {
    __builtin_amdgcn_global_load_lds(
        (const __attribute__((address_space(1))) unsigned int*)g,
        (__attribute__((address_space(3))) unsigned int*)l, 16, 0, 0);
}

__device__ __forceinline__ void gemm_tile(u16* Al, u16* Bl, int tid, int bx, int by,
                                          const u16* __restrict__ A,
                                          const u16* __restrict__ B,
                                          float* __restrict__ C,
                                          int Ndim, int Kdim)
{
    const int bm = by * 128, bn = bx * 128;
    const int wv = tid >> 6, ln = tid & 63;
    const int wr = (wv >> 1) * 64, wc = (wv & 1) * 64;
    const int fr = ln & 15, fk = (ln >> 4) * 8;

    // staging map: chunk = tid (rows 0-63) and tid+256 (rows 64-127);
    // chunk -> row = chunk>>2, col8 = (chunk&3)*8; LDS byte = chunk*16 (linear).
    const int r0 = tid >> 2, c0 = (tid & 3) * 8;
    const u16* Ap0 = A + (size_t)(bm + r0) * Kdim + c0;
    const u16* Ap1 = Ap0 + (size_t)64 * Kdim;
    const u16* Bp0 = B + (size_t)(bn + r0) * Kdim + c0;
    const u16* Bp1 = Bp0 + (size_t)64 * Kdim;
    u16* AlW0 = Al + wv * 512;          // wave-uniform LDS bases (u16 units)
    u16* AlW1 = Al + 2048 + wv * 512;
    u16* BlW0 = Bl + wv * 512;
    u16* BlW1 = Bl + 2048 + wv * 512;

    f32x4 acc[4][4];
#pragma unroll
    for (int m = 0; m < 4; ++m)
#pragma unroll
        for (int n = 0; n < 4; ++n) acc[m][n] = (f32x4)0.f;

    for (int kk = 0; kk < Kdim; kk += 32) {
        __syncthreads();
        gload_lds16(Ap0 + kk, AlW0);
        gload_lds16(Ap1 + kk, AlW1);
        gload_lds16(Bp0 + kk, BlW0);
        gload_lds16(Bp1 + kk, BlW1);
        __syncthreads();
        u16x8 af[4], bf[4];
#pragma unroll
        for (int m = 0; m < 4; ++m)
            af[m] = *(const u16x8*)&Al[(wr + m * 16 + fr) * 32 + fk];
#pragma unroll
        for (int n = 0; n < 4; ++n)
            bf[n] = *(const u16x8*)&Bl[(wc + n * 16 + fr) * 32 + fk];
#pragma unroll
        for (int m = 0; m < 4; ++m)
#pragma unroll
            for (int n = 0; n < 4; ++n)
                acc[m][n] = __builtin_amdgcn_mfma_f32_16x16x32_bf16(
                    __builtin_bit_cast(bf16x8, af[m]),
                    __builtin_bit_cast(bf16x8, bf[n]), acc[m][n], 0, 0, 0);
    }

    const int crow = (ln >> 4) * 4;
#pragma unroll
    for (int m = 0; m < 4; ++m)
#pragma unroll
        for (int n = 0; n < 4; ++n) {
            const size_t base = (size_t)(bm + wr + m * 16 + crow) * Ndim
                              + bn + wc + n * 16 + fr;
#pragma unroll
            for (int j = 0; j < 4; ++j)
                C[base + (size_t)j * Ndim] = acc[m][n][j];
        }
}

__global__ __launch_bounds__(256)
void bgemm_k(const u16* __restrict__ A, const u16* __restrict__ B,
             float* __restrict__ C, int Ndim, int Kdim)
{
    __shared__ __align__(16) unsigned char smem[SMEM_BYTES];
    gemm_tile((u16*)smem, (u16*)smem + 4096, threadIdx.x,
              blockIdx.x, blockIdx.y, A, B, C, Ndim, Kdim);
}

// ==================== f32 fallback GEMM (ws too small): C = A * B^T ====================

__global__ __launch_bounds__(256)
void g_sgemm_k(const float* __restrict__ A, const float* __restrict__ B,
               float* __restrict__ C, int Mdim, int Ndim, int Kdim)
{
    __shared__ __align__(16) float As[16][132];
    __shared__ __align__(16) float Bs[16][68];
    const int tid = threadIdx.x;
    const int tx = tid & 15, ty = tid >> 4;
    const int bn = blockIdx.x * 64, bm = blockIdx.y * 128;
    const int lrA = tid >> 1, lcA = (tid & 1) << 3;
    const int lrB = tid >> 2, lcB = (tid & 3) << 2;
    const float* Aptr = A + (size_t)(bm + lrA) * Kdim + lcA;
    const float* Bptr = B + (size_t)(bn + lrB) * Kdim + lcB;
    float4 a0 = *(const float4*)(Aptr);
    float4 a1 = *(const float4*)(Aptr + 4);
    float4 b0 = *(const float4*)(Bptr);
    float acc[8][4];
#pragma unroll
    for (int i = 0; i < 8; ++i)
#pragma unroll
        for (int j = 0; j < 4; ++j) acc[i][j] = 0.f;
    for (int kk = 0; kk < Kdim; kk += 16) {
        __syncthreads();
        As[lcA + 0][lrA] = a0.x; As[lcA + 1][lrA] = a0.y;
        As[lcA + 2][lrA] = a0.z; As[lcA + 3][lrA] = a0.w;
        As[lcA + 4][lrA] = a1.x; As[lcA + 5][lrA] = a1.y;
        As[lcA + 6][lrA] = a1.z; As[lcA + 7][lrA] = a1.w;
        Bs[lcB + 0][lrB] = b0.x; Bs[lcB + 1][lrB] = b0.y;
        Bs[lcB + 2][lrB] = b0.z; Bs[lcB + 3][lrB] = b0.w;
        __syncthreads();
        if (kk + 16 < Kdim) {
            a0 = *(const float4*)(Aptr + kk + 16);
            a1 = *(const float4*)(Aptr + kk + 20);
            b0 = *(const float4*)(Bptr + kk + 16);
        }
#pragma unroll
        for (int k = 0; k < 16; ++k) {
            const float4 av0 = *(const float4*)&As[k][ty * 8];
            const float4 av1 = *(const float4*)&As[k][ty * 8 + 4];
            const float4 bv  = *(const float4*)&Bs[k][tx * 4];
            const float avf[8] = {av0.x, av0.y, av0.z, av0.w, av1.x, av1.y, av1.z, av1.w};
            const float bvf[4] = {bv.x, bv.y, bv.z, bv.w};
#pragma unroll
            for (int i = 0; i < 8; ++i)
#pragma unroll
                for (int j = 0; j < 4; ++j) acc[i][j] += avf[i] * bvf[j];
        }
    }
#pragma unroll
    for (int i = 0; i < 8; ++i) {
        const int r = bm + ty * 8 + i;
        float4 v = {acc[i][0], acc[i][1], acc[i][2], acc[i][3]};
        *(float4*)&C[(size_t)r * Ndim + bn + tx * 4] = v;
    }
}

// ==================== spectral solve (device fn, 256 thr, H == 2048) ====================
// Truncated right-singular subspace of A = diag(a)+p q^T per jnp.linalg.pinv
// rcond, via Haynsworth inertia on A^T A = D^2 + W S W^T, W=[a.*p, q],
// S=[[0,1],[1,c]], c=p.p.  All reciprocals via frcp (f32 rcp + f64 Newton) —
// CDNA4 f64 divides are ~120cyc and were 70% of the R8 spec time.

__device__ __forceinline__ double wsum(double x) {
#pragma unroll
    for (int m = 32; m; m >>= 1) x += __shfl_xor(x, m, 64);
    return x;
}

__device__ __forceinline__ int inert(double s11, double s12, double s22,
                                     double dc, double cS)
{
    double b00 = cS - s11, b01 = -1.0 - s12, b11 = -s22;   // -S^{-1} - G
    double det = b00 * b11 - b01 * b01, tr = b00 + b11;
    int neg = (det > 0.0) ? ((tr < 0.0) ? 2 : 0) : 1;
    return (int)(dc + 0.5) + neg - 1;
}

__device__ __forceinline__ int lane_evalN4(double t, int n4,
    const float4* l0, const float4* l1, const float4* l2,
    const double* pc, bool poly, double cS,
    double& g11o, double& g12o, double& g22o)
{
    double s11 = 0, s12 = 0, s22 = 0, dc = 0;
#pragma unroll 2
    for (int i = 0; i < n4; ++i) {
        const float4 d4 = l0[i], x4 = l1[i], y4 = l2[i];
        const float dd[4] = {d4.x, d4.y, d4.z, d4.w};
        const float xx[4] = {x4.x, x4.y, x4.z, x4.w};
        const float yy[4] = {y4.x, y4.y, y4.z, y4.w};
#pragma unroll
        for (int e = 0; e < 4; ++e) {
            double den = (double)dd[e] - t;
            if (fabs(den) < 1e-25) den = (den < 0 ? -1e-25 : 1e-25);
            double inv = frcp(den);
            double b1 = (double)xx[e], b2 = (double)yy[e];
            s11 += b1 * b1 * inv; s12 += b1 * b2 * inv; s22 += b2 * b2 * inv;
            if ((double)dd[e] < t) dc += 1.0;
        }
    }
    if (poly) {
        s11 += pc[0] + t * (pc[3] + t * (pc[6] + t * pc[9]));
        s12 += pc[1] + t * (pc[4] + t * (pc[7] + t * pc[10]));
        s22 += pc[2] + t * (pc[5] + t * (pc[8] + t * pc[11]));
    }
    g11o = s11; g12o = s12; g22o = s22;
    return inert(s11, s12, s22, dc, cS);
}

__device__ void spec256(unsigned char* smem, int tid,
                        const float* __restrict__ av, const float* __restrict__ pv,
                        const float* __restrict__ qv, double* __restrict__ hdr,
                        float* __restrict__ V)
{
    float* sd2 = (float*)smem;          // 2048
    float* sw1 = sd2 + 2048;
    float* sw2 = sw1 + 2048;
    float* nl0 = sw2 + 2048;            // NL_CAP each
    float* nl1 = nl0 + NL_CAP;
    float* nl2 = nl1 + NL_CAP;
    double* dsh = (double*)(nl2 + NL_CAP);   // 192 doubles
    int* ish = (int*)(dsh + 192);            // 16 ints

    const int lane = tid & 63, wv = tid >> 6;
    const int j0 = tid * 8;

    float d2r[8], w1r[8], w2r[8];
    double cS = 0, n1 = 0, n2 = 0, mx = 0;
#pragma unroll
    for (int h = 0; h < 2; ++h) {
        float4 aa = *(const float4*)&av[j0 + h * 4];
        float4 pp = *(const float4*)&pv[j0 + h * 4];
        float4 qq = *(const float4*)&qv[j0 + h * 4];
        const float a4[4] = {aa.x, aa.y, aa.z, aa.w};
        const float p4[4] = {pp.x, pp.y, pp.z, pp.w};
        const float q4[4] = {qq.x, qq.y, qq.z, qq.w};
#pragma unroll
        for (int e = 0; e < 4; ++e) {
            const int ix = h * 4 + e;
            d2r[ix] = a4[e] * a4[e];
            w1r[ix] = a4[e] * p4[e];
            w2r[ix] = q4[e];
            sd2[j0 + ix] = d2r[ix]; sw1[j0 + ix] = w1r[ix]; sw2[j0 + ix] = w2r[ix];
            cS += (double)p4[e] * p4[e];
            n1 += (double)w1r[ix] * w1r[ix];
            n2 += (double)w2r[ix] * w2r[ix];
            mx = fmax(mx, (double)d2r[ix]);
        }
    }
    cS = wsum(cS); n1 = wsum(n1); n2 = wsum(n2);
#pragma unroll
    for (int m_ = 32; m_; m_ >>= 1) mx = fmax(mx, __shfl_xor(mx, m_, 64));
    __syncthreads();
    if (lane == 0) { dsh[wv] = cS; dsh[4 + wv] = n1; dsh[8 + wv] = n2; dsh[12 + wv] = mx; }
    __syncthreads();
    cS = 0; n1 = 0; n2 = 0; mx = 0;
    for (int w = 0; w < 4; ++w) {
        cS += dsh[w]; n1 += dsh[4 + w]; n2 += dsh[8 + w];
        mx = fmax(mx, dsh[12 + w]);
    }
    __syncthreads();

    // ---- Phase A: lambda_max 5-section x 8 rounds ----
    double lo = 0.0;
    double hi = mx + 0.5 * (cS + sqrt(cS * cS + 4.0)) * (n1 + n2) + 1.0;
    for (int r = 0; r < 8; ++r) {
        const double t = lo + (hi - lo) * (double)(wv + 1) / 5.0;
        double s11 = 0, s12 = 0, s22 = 0, dc = 0;
        for (int i4 = lane; i4 < 512; i4 += 64) {
            const float4 dd = ((const float4*)sd2)[i4];
            const float4 e1 = ((const float4*)sw1)[i4];
            const float4 e2 = ((const float4*)sw2)[i4];
            const float df[4] = {dd.x, dd.y, dd.z, dd.w};
            const float f1[4] = {e1.x, e1.y, e1.z, e1.w};
            const float f2[4] = {e2.x, e2.y, e2.z, e2.w};
#pragma unroll
            for (int e = 0; e < 4; ++e) {
                double den = (double)df[e] - t;
                if (fabs(den) < 1e-25) den = (den < 0 ? -1e-25 : 1e-25);
                double inv = frcp(den);
                double b1 = (double)f1[e], b2 = (double)f2[e];
                s11 += b1 * b1 * inv; s12 += b1 * b2 * inv; s22 += b2 * b2 * inv;
                if ((double)df[e] < t) dc += 1.0;
            }
        }
        s11 = wsum(s11); s12 = wsum(s12); s22 = wsum(s22); dc = wsum(dc);
        if (lane == 0) ish[wv] = inert(s11, s12, s22, dc, cS);
        __syncthreads();
        double nlo = lo, nhi = hi;
        for (int i = 0; i < 4; ++i) {
            double ti = lo + (hi - lo) * (double)(i + 1) / 5.0;
            if (ish[i] >= 2048) { if (ti < nhi) nhi = ti; }
            else                { if (ti > nlo) nlo = ti; }
        }
        lo = nlo; hi = nhi;
        __syncthreads();
    }
    const double lmax = 0.5 * (lo + hi);
    const double rc = 10.0 * 2048.0 * 1.1920928955078125e-07;
    const double cut2 = rc * rc * lmax;

    // ---- Phase B: deterministic near-list compaction + far Taylor coeffs ----
    int flags = 0, lc = 0;
#pragma unroll
    for (int e = 0; e < 8; ++e)
        if (d2r[e] < THETA) { flags |= (1 << e); ++lc; }
    int sc = lc;
#pragma unroll
    for (int off = 1; off < 64; off <<= 1) {
        int y = __shfl_up(sc, off, 64);
        if (lane >= off) sc += y;
    }
    const int wtot = __shfl(sc, 63, 64);
    const int excl = sc - lc;
    if (lane == 0) ish[4 + wv] = wtot;
    __syncthreads();
    int base = excl;
    for (int w = 0; w < wv; ++w) base += ish[4 + w];
    int cnt = 0;
    for (int w = 0; w < 4; ++w) cnt += ish[4 + w];
    {
        int pos = base;
#pragma unroll
        for (int e = 0; e < 8; ++e) {
            if (flags & (1 << e)) {
                if (pos < NL_CAP) { nl0[pos] = d2r[e]; nl1[pos] = w1r[e]; nl2[pos] = w2r[e]; }
                ++pos;
            }
        }
    }
    const int cntPad = (cnt + 7) & ~7;
    if (tid == 0) {
        for (int i = cnt; i < cntPad && i < NL_CAP; ++i) {
            nl0[i] = 1e30f; nl1[i] = 0.f; nl2[i] = 0.f;   // exact no-op entries
        }
        ish[8] = cnt; ish[10] = cntPad >> 2;
    }

    double cf[12];
#pragma unroll
    for (int c = 0; c < 12; ++c) cf[c] = 0;
#pragma unroll
    for (int e = 0; e < 8; ++e) {
        if (d2r[e] >= THETA) {
            double id = frcp((double)d2r[e]);
            double b1 = (double)w1r[e], b2 = (double)w2r[e];
            double x11 = b1 * b1, x12 = b1 * b2, x22 = b2 * b2;
            double f = id;
            cf[0] += x11 * f; cf[1]  += x12 * f; cf[2]  += x22 * f; f *= id;
            cf[3] += x11 * f; cf[4]  += x12 * f; cf[5]  += x22 * f; f *= id;
            cf[6] += x11 * f; cf[7]  += x12 * f; cf[8]  += x22 * f; f *= id;
            cf[9] += x11 * f; cf[10] += x12 * f; cf[11] += x22 * f;
        }
    }
#pragma unroll
    for (int c = 0; c < 12; ++c) cf[c] = wsum(cf[c]);
    if (lane == 0) {
        double* dw = &dsh[16 + wv * 12];
#pragma unroll
        for (int c = 0; c < 12; ++c) dw[c] = cf[c];
    }
    __syncthreads();
    if (tid < 12) {
        double s = 0;
        for (int w = 0; w < 4; ++w) s += dsh[16 + w * 12 + tid];
        dsh[96 + tid] = s;
    }
    __syncthreads();

    cnt = ish[8];
    const bool nearOK = (cnt <= NL_CAP - 8);
    const float4* l0 = nearOK ? (const float4*)nl0 : (const float4*)sd2;
    const float4* l1 = nearOK ? (const float4*)nl1 : (const float4*)sw1;
    const float4* l2 = nearOK ? (const float4*)nl2 : (const float4*)sw2;
    const int n4 = nearOK ? ish[10] : 512;
    const bool poly = nearOK;
    const double* pcoef = &dsh[96];

    double zg1, zg2, zg3;
    if (wv == 0) {
        int N = lane_evalN4(cut2, n4, l0, l1, l2, pcoef, poly, cS, zg1, zg2, zg3);
        if (lane == 0) ish[9] = N;
    }
    __syncthreads();
    int m = ish[9];
    if (m < 0) m = 0;
    if (m > MAXM) m = MAXM;

    // ---- Phase C: per-lane 65-section, eigenvalues striped over 4 waves ----
    for (int k = wv; k < m; k += 4) {
        double klo = 0.0, khi = cut2;
        for (int r = 0; r < 4; ++r) {
            const double w = khi - klo;
            const double t = klo + w * (double)(lane + 1) / 65.0;
            int N = lane_evalN4(t, n4, l0, l1, l2, pcoef, poly, cS, zg1, zg2, zg3);
            unsigned long long mask = __ballot(N >= k + 1);
            int j = (mask == 0ull) ? 64 : (__ffsll(mask) - 1);
            double nk = (j == 64) ? khi : (klo + w * (double)(j + 1) / 65.0);
            klo = klo + w * (double)j / 65.0;
            khi = nk;
        }
        const double lam = 0.5 * (klo + khi);
        double g11, g12, g22;
        lane_evalN4(lam, n4, l0, l1, l2, pcoef, poly, cS, g11, g12, g22);
        const double m00 = 1.0 + g12, m01 = g11 + cS * g12;
        const double m10 = g22,       m11 = 1.0 + g12 + cS * g22;
        double y1, y2;
        if (m00 * m00 + m01 * m01 >= m10 * m10 + m11 * m11) { y1 = m01; y2 = -m00; }
        else                                                { y1 = m11; y2 = -m10; }
        if (lane == 0) {
            dsh[112 + 3 * k]     = lam;
            dsh[112 + 3 * k + 1] = y2;             // z1
            dsh[112 + 3 * k + 2] = y1 + cS * y2;   // z2
        }
    }
    __syncthreads();

    // ---- Phase D: full eigenvectors + f64 norms ----
    for (int k = 0; k < m; ++k) {
        const double lam = dsh[112 + 3 * k];
        const double z1 = dsh[112 + 3 * k + 1], z2 = dsh[112 + 3 * k + 2];
        double vr[8], pn = 0;
#pragma unroll
        for (int e = 0; e < 8; ++e) {
            double den = (double)d2r[e] - lam;
            if (fabs(den) < 1e-25) den = (den < 0 ? -1e-25 : 1e-25);
            vr[e] = ((double)w1r[e] * z1 + (double)w2r[e] * z2) * frcp(den);
            pn += vr[e] * vr[e];
        }
        pn = wsum(pn);
        if (lane == 0) dsh[160 + wv] = pn;
        __syncthreads();
        double tot = 0;
        for (int w = 0; w < 4; ++w) tot += dsh[160 + w];
        const double inv = 1.0 / sqrt(tot);
        float o0[8];
#pragma unroll
        for (int e = 0; e < 8; ++e) o0[e] = (float)(vr[e] * inv);
        *(float4*)&V[(size_t)k * 2048 + j0]     = *(float4*)&o0[0];
        *(float4*)&V[(size_t)k * 2048 + j0 + 4] = *(float4*)&o0[4];
        __syncthreads();
    }

    if (tid == 0) { hdr[0] = lmax; hdr[1] = cut2; hdr[2] = (double)m; hdr[3] = cS; }
}

// ==================== fat kernel: block 0 = spec, blocks 1..ntiles = GEMM ====================

__global__ __launch_bounds__(256)
void fat_k(const u16* __restrict__ A, const u16* __restrict__ B,
           float* __restrict__ C, int Ndim, int Kdim, int ntiles, int nbx,
           const float* __restrict__ av, const float* __restrict__ pv,
           const float* __restrict__ qv, double* __restrict__ hdr,
           float* __restrict__ V)
{
    __shared__ __align__(16) unsigned char smem[SMEM_BYTES];
    const int bid = blockIdx.x;
    if (bid == 0) {
        spec256(smem, threadIdx.x, av, pv, qv, hdr, V);
        return;
    }
    if (bid - 1 >= ntiles) return;
    const int t = bid - 1;
    gemm_tile((u16*)smem, (u16*)smem + 4096, threadIdx.x,
              t % nbx, t / nbx, A, B, C, Ndim, Kdim);
}

// ==================== wave-per-row fused series kernel (H == 2048) ====================
// io holds U = x b^T on entry; on exit io = out.
//   o = [sum_{k=0..13} U (M^T)^k/(k+1)!] * d ; o -= P_V o ; o += sum_{k=0..14} h (M^T)^k/k!

__global__ __launch_bounds__(256, 2)
void series_k(float* __restrict__ io, const float* __restrict__ hm,
              const float* __restrict__ qv, const float* __restrict__ pv,
              const float* __restrict__ av, const float* __restrict__ delta,
              const float* __restrict__ V, const double* __restrict__ hdr,
              int useTrunc)
{
    const int lane = threadIdx.x & 63;
    const int row = blockIdx.x * 4 + (threadIdx.x >> 6);
    const float d = delta[0];
    const int m = useTrunc ? (int)hdr[2] : 0;

    float q[32], p[32], a[32], t[32], o[32];
    float* iorow = io + (size_t)row * 2048;
#pragma unroll
    for (int cc = 0; cc < 8; ++cc) {
        const int j = cc * 256 + lane * 4;
        *(float4*)&q[cc * 4] = *(const float4*)&qv[j];
        *(float4*)&p[cc * 4] = *(const float4*)&pv[j];
        *(float4*)&a[cc * 4] = *(const float4*)&av[j];
        *(float4*)&t[cc * 4] = *(const float4*)&iorow[j];
    }
#pragma unroll
    for (int e = 0; e < 32; ++e) o[e] = t[e];

    float cf = 1.f;
    for (int k = 1; k <= 13; ++k) {
        float s = 0.f;
#pragma unroll
        for (int e = 0; e < 32; ++e) s += t[e] * q[e];
#pragma unroll
        for (int msk = 32; msk; msk >>= 1) s += __shfl_xor(s, msk, 64);
        cf /= (float)(k + 1);
        const float ds = d * s;
#pragma unroll
        for (int e = 0; e < 32; ++e) { t[e] = d * a[e] * t[e] + ds * p[e]; o[e] += cf * t[e]; }
    }
#pragma unroll
    for (int e = 0; e < 32; ++e) o[e] *= d;

    for (int k = 0; k < m; ++k) {
        const float* vr = V + (size_t)k * 2048;
        float vk[32];
#pragma unroll
        for (int cc = 0; cc < 8; ++cc)
            *(float4*)&vk[cc * 4] = *(const float4*)&vr[cc * 256 + lane * 4];
        float s = 0.f;
#pragma unroll
        for (int e = 0; e < 32; ++e) s += o[e] * vk[e];
#pragma unroll
        for (int msk = 32; msk; msk >>= 1) s += __shfl_xor(s, msk, 64);
#pragma unroll
        for (int e = 0; e < 32; ++e) o[e] -= s * vk[e];
    }

    const float* hrow = hm + (size_t)row * 2048;
#pragma unroll
    for (int cc = 0; cc < 8; ++cc)
        *(float4*)&t[cc * 4] = *(const float4*)&hrow[cc * 256 + lane * 4];
#pragma unroll
    for (int e = 0; e < 32; ++e) o[e] += t[e];
    cf = 1.f;
    for (int k = 1; k <= 14; ++k) {
        float s = 0.f;
#pragma unroll
        for (int e = 0; e < 32; ++e) s += t[e] * q[e];
#pragma unroll
        for (int msk = 32; msk; msk >>= 1) s += __shfl_xor(s, msk, 64);
        cf /= (float)k;
        const float ds = d * s;
#pragma unroll
        for (int e = 0; e < 32; ++e) { t[e] = d * a[e] * t[e] + ds * p[e]; o[e] += cf * t[e]; }
    }
#pragma unroll
    for (int cc = 0; cc < 8; ++cc)
        *(float4*)&iorow[cc * 256 + lane * 4] = *(const float4*)&o[cc * 4];
}

// ==================== host orchestration ====================
// out = h expm(dA)^T + d*(x b^T) phi1(dA^T) (I - P_V);  P_V = truncated
// right-singular subspace of A per jnp.linalg.pinv rcond (exact identity).
// conv -> fat(spec block 0 || 256 GEMM tiles) -> series.

extern "C" void kernel_launch(void* const* d_in, const int* in_sizes, int n_in,
                              void* d_out, int out_size, void* d_ws, size_t ws_size,
                              hipStream_t stream)
{
    const float* hmat  = (const float*)d_in[0];
    const float* xmat  = (const float*)d_in[1];
    const float* adiag = (const float*)d_in[2];
    const float* pvec  = (const float*)d_in[3];
    const float* qvec  = (const float*)d_in[4];
    const float* bmat  = (const float*)d_in[5];
    const float* delta = (const float*)d_in[6];
    float* out = (float*)d_out;

    const int H  = in_sizes[2];
    const int Bb = in_sizes[0] / H;
    const size_t SZ = (size_t)Bb * H;
    const size_t HH = (size_t)H * H;

    double* hdr = (double*)d_ws;
    float* V = (float*)(hdr + 8);
    u16* xb = (u16*)(V + (size_t)MAXM * H);
    u16* bb = xb + SZ;

    const size_t needSpec = 64 + (size_t)MAXM * H * sizeof(float);
    const size_t needFull = needSpec + (SZ + HH) * sizeof(u16);
    const bool doTrunc = (H == 2048) && (ws_size >= needSpec);
    const bool doBf16  = (ws_size >= needFull) && (H % 128 == 0) && (Bb % 128 == 0);

    dim3 blk256(256);
    const int nbx = H / 128;
    const int ntiles = nbx * (Bb / 128);

    if (doBf16) {
        const long nmax = (long)(SZ > HH ? SZ : HH);
        const int cg = (int)((nmax / 4 + 255) / 256);
        conv_k<<<cg, blk256, 0, stream>>>(xmat, bmat, xb, bb, (long)SZ, (long)HH);
        if (doTrunc) {
            fat_k<<<1 + ntiles, blk256, 0, stream>>>(xb, bb, out, H, H, ntiles, nbx,
                                                     adiag, pvec, qvec, hdr, V);
        } else {
            dim3 gg(nbx, Bb / 128);
            bgemm_k<<<gg, blk256, 0, stream>>>(xb, bb, out, H, H);
        }
    } else {
        if (doTrunc)
            fat_k<<<1, blk256, 0, stream>>>(nullptr, nullptr, out, H, H, 0, 1,
                                            adiag, pvec, qvec, hdr, V);
        dim3 gg(H / 64, Bb / 128);
        g_sgemm_k<<<gg, blk256, 0, stream>>>(xmat, bmat, out, Bb, H, H);
    }

    // fused series + projection, in-place on d_out
    series_k<<<Bb / 4, blk256, 0, stream>>>(out, hmat, qvec, pvec, adiag, delta,
                                            V, hdr, doTrunc ? 1 : 0);
}

// Round 10
// 91.421 us; speedup vs baseline: 1.9541x; 1.2721x over previous
//
#include <hip/hip_runtime.h>

#define MAXM 16
#define NL_CAP 256
#define THETA 0.1f
#define SMEM_BYTES 36864

typedef unsigned short u16;
typedef u16 u16x8 __attribute__((ext_vector_type(8)));
typedef u16 u16x4 __attribute__((ext_vector_type(4)));
typedef __bf16 bf16x8 __attribute__((ext_vector_type(8)));
typedef float f32x4 __attribute__((ext_vector_type(4)));

// ==================== f32 -> bf16 (RNE) ====================

__device__ __forceinline__ u16 f2bf(float f) {
    unsigned u = __float_as_uint(f);
    return (u16)((u + 0x7fffu + ((u >> 16) & 1u)) >> 16);
}

__global__ __launch_bounds__(256)
void conv_k(const float* __restrict__ x, const float* __restrict__ b,
            u16* __restrict__ xb, u16* __restrict__ bb, long nx, long nb)
{
    long i = ((long)blockIdx.x * 256 + threadIdx.x) * 4;
    if (i < nx) {
        float4 v = *(const float4*)&x[i];
        u16x4 o = {f2bf(v.x), f2bf(v.y), f2bf(v.z), f2bf(v.w)};
        *(u16x4*)&xb[i] = o;
    }
    if (i < nb) {
        float4 v = *(const float4*)&b[i];
        u16x4 o = {f2bf(v.x), f2bf(v.y), f2bf(v.z), f2bf(v.w)};
        *(u16x4*)&bb[i] = o;
    }
}

// ==================== fast f64 reciprocal (Phase B/D only) ====================

__device__ __forceinline__ double frcp(double den) {
    double r = (double)__builtin_amdgcn_rcpf((float)den);
    return fma(r, fma(-den, r, 1.0), r);
}

// ==================== bf16 MFMA GEMM tile (device fn) ====================

__device__ __forceinline__ void gload_lds16(const void* g, void* l) {
    __builtin_amdgcn_global_load_lds(
        (const __attribute__((address_space(1))) unsigned int*)g,
        (__attribute__((address_space(3))) unsigned int*)l, 16, 0, 0);
}

__device__ __forceinline__ void gemm_tile(u16* Al, u16* Bl, int tid, int bx, int by,
                                          const u16* __restrict__ A,
                                          const u16* __restrict__ B,
                                          float* __restrict__ C,
                                          int Ndim, int Kdim)
{
    const int bm = by * 128, bn = bx * 128;
    const int wv = tid >> 6, ln = tid & 63;
    const int wr = (wv >> 1) * 64, wc = (wv & 1) * 64;
    const int fr = ln & 15, fk = (ln >> 4) * 8;

    const int r0 = tid >> 2, c0 = (tid & 3) * 8;
    const u16* Ap0 = A + (size_t)(bm + r0) * Kdim + c0;
    const u16* Ap1 = Ap0 + (size_t)64 * Kdim;
    const u16* Bp0 = B + (size_t)(bn + r0) * Kdim + c0;
    const u16* Bp1 = Bp0 + (size_t)64 * Kdim;
    u16* AlW0 = Al + wv * 512;
    u16* AlW1 = Al + 2048 + wv * 512;
    u16* BlW0 = Bl + wv * 512;
    u16* BlW1 = Bl + 2048 + wv * 512;

    f32x4 acc[4][4];
#pragma unroll
    for (int m = 0; m < 4; ++m)
#pragma unroll
        for (int n = 0; n < 4; ++n) acc[m][n] = (f32x4)0.f;

    for (int kk = 0; kk < Kdim; kk += 32) {
        __syncthreads();
        gload_lds16(Ap0 + kk, AlW0);
        gload_lds16(Ap1 + kk, AlW1);
        gload_lds16(Bp0 + kk, BlW0);
        gload_lds16(Bp1 + kk, BlW1);
        __syncthreads();
        u16x8 af[4], bf[4];
#pragma unroll
        for (int m = 0; m < 4; ++m)
            af[m] = *(const u16x8*)&Al[(wr + m * 16 + fr) * 32 + fk];
#pragma unroll
        for (int n = 0; n < 4; ++n)
            bf[n] = *(const u16x8*)&Bl[(wc + n * 16 + fr) * 32 + fk];
#pragma unroll
        for (int m = 0; m < 4; ++m)
#pragma unroll
            for (int n = 0; n < 4; ++n)
                acc[m][n] = __builtin_amdgcn_mfma_f32_16x16x32_bf16(
                    __builtin_bit_cast(bf16x8, af[m]),
                    __builtin_bit_cast(bf16x8, bf[n]), acc[m][n], 0, 0, 0);
    }

    const int crow = (ln >> 4) * 4;
#pragma unroll
    for (int m = 0; m < 4; ++m)
#pragma unroll
        for (int n = 0; n < 4; ++n) {
            const size_t base = (size_t)(bm + wr + m * 16 + crow) * Ndim
                              + bn + wc + n * 16 + fr;
#pragma unroll
            for (int j = 0; j < 4; ++j)
                C[base + (size_t)j * Ndim] = acc[m][n][j];
        }
}

__global__ __launch_bounds__(256)
void bgemm_k(const u16* __restrict__ A, const u16* __restrict__ B,
             float* __restrict__ C, int Ndim, int Kdim)
{
    __shared__ __align__(16) unsigned char smem[SMEM_BYTES];
    gemm_tile((u16*)smem, (u16*)smem + 4096, threadIdx.x,
              blockIdx.x, blockIdx.y, A, B, C, Ndim, Kdim);
}

// ==================== f32 fallback GEMM (ws too small) ====================

__global__ __launch_bounds__(256)
void g_sgemm_k(const float* __restrict__ A, const float* __restrict__ B,
               float* __restrict__ C, int Mdim, int Ndim, int Kdim)
{
    __shared__ __align__(16) float As[16][132];
    __shared__ __align__(16) float Bs[16][68];
    const int tid = threadIdx.x;
    const int tx = tid & 15, ty = tid >> 4;
    const int bn = blockIdx.x * 64, bm = blockIdx.y * 128;
    const int lrA = tid >> 1, lcA = (tid & 1) << 3;
    const int lrB = tid >> 2, lcB = (tid & 3) << 2;
    const float* Aptr = A + (size_t)(bm + lrA) * Kdim + lcA;
    const float* Bptr = B + (size_t)(bn + lrB) * Kdim + lcB;
    float4 a0 = *(const float4*)(Aptr);
    float4 a1 = *(const float4*)(Aptr + 4);
    float4 b0 = *(const float4*)(Bptr);
    float acc[8][4];
#pragma unroll
    for (int i = 0; i < 8; ++i)
#pragma unroll
        for (int j = 0; j < 4; ++j) acc[i][j] = 0.f;
    for (int kk = 0; kk < Kdim; kk += 16) {
        __syncthreads();
        As[lcA + 0][lrA] = a0.x; As[lcA + 1][lrA] = a0.y;
        As[lcA + 2][lrA] = a0.z; As[lcA + 3][lrA] = a0.w;
        As[lcA + 4][lrA] = a1.x; As[lcA + 5][lrA] = a1.y;
        As[lcA + 6][lrA] = a1.z; As[lcA + 7][lrA] = a1.w;
        Bs[lcB + 0][lrB] = b0.x; Bs[lcB + 1][lrB] = b0.y;
        Bs[lcB + 2][lrB] = b0.z; Bs[lcB + 3][lrB] = b0.w;
        __syncthreads();
        if (kk + 16 < Kdim) {
            a0 = *(const float4*)(Aptr + kk + 16);
            a1 = *(const float4*)(Aptr + kk + 20);
            b0 = *(const float4*)(Bptr + kk + 16);
        }
#pragma unroll
        for (int k = 0; k < 16; ++k) {
            const float4 av0 = *(const float4*)&As[k][ty * 8];
            const float4 av1 = *(const float4*)&As[k][ty * 8 + 4];
            const float4 bv  = *(const float4*)&Bs[k][tx * 4];
            const float avf[8] = {av0.x, av0.y, av0.z, av0.w, av1.x, av1.y, av1.z, av1.w};
            const float bvf[4] = {bv.x, bv.y, bv.z, bv.w};
#pragma unroll
            for (int i = 0; i < 8; ++i)
#pragma unroll
                for (int j = 0; j < 4; ++j) acc[i][j] += avf[i] * bvf[j];
        }
    }
#pragma unroll
    for (int i = 0; i < 8; ++i) {
        const int r = bm + ty * 8 + i;
        float4 v = {acc[i][0], acc[i][1], acc[i][2], acc[i][3]};
        *(float4*)&C[(size_t)r * Ndim + bn + tx * 4] = v;
    }
}

// ==================== spectral solve (device fn, 256 thr, H == 2048) ====================
// Haynsworth inertia on A^T A = D^2 + W S W^T; hot secular evals in F32
// (f64 vector ops measured ~8cyc effective on gfx950 -> they were the whole
// spec cost). f32 noise shifts eigenvalues ~2e-9 << pole gap ~2.5e-4.

__device__ __forceinline__ double wsum(double x) {
#pragma unroll
    for (int m = 32; m; m >>= 1) x += __shfl_xor(x, m, 64);
    return x;
}
__device__ __forceinline__ float wsumf(float x) {
#pragma unroll
    for (int m = 32; m; m >>= 1) x += __shfl_xor(x, m, 64);
    return x;
}

__device__ __forceinline__ int inert(double s11, double s12, double s22,
                                     double dc, double cS)
{
    double b00 = cS - s11, b01 = -1.0 - s12, b11 = -s22;   // -S^{-1} - G
    double det = b00 * b11 - b01 * b01, tr = b00 + b11;
    int neg = (det > 0.0) ? ((tr < 0.0) ? 2 : 0) : 1;
    return (int)(dc + 0.5) + neg - 1;
}

// per-lane f32 secular eval over compacted list + f64 far-poly correction
__device__ __forceinline__ int lane_evalN32(float tf, double td, int n4,
    const float4* l0, const float4* l1, const float4* l2,
    const double* pc, bool poly, double cS,
    double& g11o, double& g12o, double& g22o)
{
    float s11 = 0.f, s12 = 0.f, s22 = 0.f, dc = 0.f;
#pragma unroll 2
    for (int i = 0; i < n4; ++i) {
        const float4 d4 = l0[i], x4 = l1[i], y4 = l2[i];
        const float dd[4] = {d4.x, d4.y, d4.z, d4.w};
        const float xx[4] = {x4.x, x4.y, x4.z, x4.w};
        const float yy[4] = {y4.x, y4.y, y4.z, y4.w};
#pragma unroll
        for (int e = 0; e < 4; ++e) {
            float den = dd[e] - tf;
            float mag = fmaxf(fabsf(den), 1e-30f);
            den = (den < 0.f) ? -mag : mag;
            const float inv = __builtin_amdgcn_rcpf(den);
            s11 = fmaf(xx[e] * xx[e], inv, s11);
            s12 = fmaf(xx[e] * yy[e], inv, s12);
            s22 = fmaf(yy[e] * yy[e], inv, s22);
            if (dd[e] < tf) dc += 1.f;
        }
    }
    double S11 = (double)s11, S12 = (double)s12, S22 = (double)s22;
    if (poly) {
        S11 += pc[0] + td * (pc[3] + td * (pc[6] + td * pc[9]));
        S12 += pc[1] + td * (pc[4] + td * (pc[7] + td * pc[10]));
        S22 += pc[2] + td * (pc[5] + td * (pc[8] + td * pc[11]));
    }
    g11o = S11; g12o = S12; g22o = S22;
    return inert(S11, S12, S22, (double)dc, cS);
}

__device__ void spec256(unsigned char* smem, int tid,
                        const float* __restrict__ av, const float* __restrict__ pv,
                        const float* __restrict__ qv, double* __restrict__ hdr,
                        float* __restrict__ V)
{
    float* sd2 = (float*)smem;          // 2048
    float* sw1 = sd2 + 2048;
    float* sw2 = sw1 + 2048;
    float* nl0 = sw2 + 2048;            // NL_CAP each
    float* nl1 = nl0 + NL_CAP;
    float* nl2 = nl1 + NL_CAP;
    double* dsh = (double*)(nl2 + NL_CAP);   // 192 doubles
    int* ish = (int*)(dsh + 192);            // 16 ints

    const int lane = tid & 63, wv = tid >> 6;
    const int j0 = tid * 8;

    float d2r[8], w1r[8], w2r[8];
    double cS = 0, n1 = 0, n2 = 0, mx = 0;
#pragma unroll
    for (int h = 0; h < 2; ++h) {
        float4 aa = *(const float4*)&av[j0 + h * 4];
        float4 pp = *(const float4*)&pv[j0 + h * 4];
        float4 qq = *(const float4*)&qv[j0 + h * 4];
        const float a4[4] = {aa.x, aa.y, aa.z, aa.w};
        const float p4[4] = {pp.x, pp.y, pp.z, pp.w};
        const float q4[4] = {qq.x, qq.y, qq.z, qq.w};
#pragma unroll
        for (int e = 0; e < 4; ++e) {
            const int ix = h * 4 + e;
            d2r[ix] = a4[e] * a4[e];
            w1r[ix] = a4[e] * p4[e];
            w2r[ix] = q4[e];
            sd2[j0 + ix] = d2r[ix]; sw1[j0 + ix] = w1r[ix]; sw2[j0 + ix] = w2r[ix];
            cS += (double)p4[e] * p4[e];
            n1 += (double)w1r[ix] * w1r[ix];
            n2 += (double)w2r[ix] * w2r[ix];
            mx = fmax(mx, (double)d2r[ix]);
        }
    }
    cS = wsum(cS); n1 = wsum(n1); n2 = wsum(n2);
#pragma unroll
    for (int m_ = 32; m_; m_ >>= 1) mx = fmax(mx, __shfl_xor(mx, m_, 64));
    __syncthreads();
    if (lane == 0) { dsh[wv] = cS; dsh[4 + wv] = n1; dsh[8 + wv] = n2; dsh[12 + wv] = mx; }
    __syncthreads();
    cS = 0; n1 = 0; n2 = 0; mx = 0;
    for (int w = 0; w < 4; ++w) {
        cS += dsh[w]; n1 += dsh[4 + w]; n2 += dsh[8 + w];
        mx = fmax(mx, dsh[12 + w]);
    }
    __syncthreads();

    // ---- Phase A: lambda_max 5-section x 8 rounds, f32 scans ----
    double lo = 0.0;
    double hi = mx + 0.5 * (cS + sqrt(cS * cS + 4.0)) * (n1 + n2) + 1.0;
    for (int r = 0; r < 8; ++r) {
        const double td = lo + (hi - lo) * (double)(wv + 1) / 5.0;
        const float tf = (float)td;
        float s11 = 0.f, s12 = 0.f, s22 = 0.f, dc = 0.f;
        for (int i4 = lane; i4 < 512; i4 += 64) {
            const float4 dd = ((const float4*)sd2)[i4];
            const float4 e1 = ((const float4*)sw1)[i4];
            const float4 e2 = ((const float4*)sw2)[i4];
            const float df[4] = {dd.x, dd.y, dd.z, dd.w};
            const float f1[4] = {e1.x, e1.y, e1.z, e1.w};
            const float f2[4] = {e2.x, e2.y, e2.z, e2.w};
#pragma unroll
            for (int e = 0; e < 4; ++e) {
                float den = df[e] - tf;
                float mag = fmaxf(fabsf(den), 1e-30f);
                den = (den < 0.f) ? -mag : mag;
                const float inv = __builtin_amdgcn_rcpf(den);
                s11 = fmaf(f1[e] * f1[e], inv, s11);
                s12 = fmaf(f1[e] * f2[e], inv, s12);
                s22 = fmaf(f2[e] * f2[e], inv, s22);
                if (df[e] < tf) dc += 1.f;
            }
        }
        s11 = wsumf(s11); s12 = wsumf(s12); s22 = wsumf(s22); dc = wsumf(dc);
        if (lane == 0)
            ish[wv] = inert((double)s11, (double)s12, (double)s22, (double)dc, cS);
        __syncthreads();
        double nlo = lo, nhi = hi;
        for (int i = 0; i < 4; ++i) {
            double ti = lo + (hi - lo) * (double)(i + 1) / 5.0;
            if (ish[i] >= 2048) { if (ti < nhi) nhi = ti; }
            else                { if (ti > nlo) nlo = ti; }
        }
        lo = nlo; hi = nhi;
        __syncthreads();
    }
    const double lmax = 0.5 * (lo + hi);
    const double rc = 10.0 * 2048.0 * 1.1920928955078125e-07;
    const double cut2 = rc * rc * lmax;

    // ---- Phase B: deterministic near-list compaction + far Taylor coeffs (f64, once) ----
    int flags = 0, lc = 0;
#pragma unroll
    for (int e = 0; e < 8; ++e)
        if (d2r[e] < THETA) { flags |= (1 << e); ++lc; }
    int sc = lc;
#pragma unroll
    for (int off = 1; off < 64; off <<= 1) {
        int y = __shfl_up(sc, off, 64);
        if (lane >= off) sc += y;
    }
    const int wtot = __shfl(sc, 63, 64);
    const int excl = sc - lc;
    if (lane == 0) ish[4 + wv] = wtot;
    __syncthreads();
    int base = excl;
    for (int w = 0; w < wv; ++w) base += ish[4 + w];
    int cnt = 0;
    for (int w = 0; w < 4; ++w) cnt += ish[4 + w];
    {
        int pos = base;
#pragma unroll
        for (int e = 0; e < 8; ++e) {
            if (flags & (1 << e)) {
                if (pos < NL_CAP) { nl0[pos] = d2r[e]; nl1[pos] = w1r[e]; nl2[pos] = w2r[e]; }
                ++pos;
            }
        }
    }
    const int cntPad = (cnt + 7) & ~7;
    if (tid == 0) {
        for (int i = cnt; i < cntPad && i < NL_CAP; ++i) {
            nl0[i] = 1e30f; nl1[i] = 0.f; nl2[i] = 0.f;   // exact no-op entries
        }
        ish[8] = cnt; ish[10] = cntPad >> 2;
    }

    double cf[12];
#pragma unroll
    for (int c = 0; c < 12; ++c) cf[c] = 0;
#pragma unroll
    for (int e = 0; e < 8; ++e) {
        if (d2r[e] >= THETA) {
            double id = frcp((double)d2r[e]);
            double b1 = (double)w1r[e], b2 = (double)w2r[e];
            double x11 = b1 * b1, x12 = b1 * b2, x22 = b2 * b2;
            double f = id;
            cf[0] += x11 * f; cf[1]  += x12 * f; cf[2]  += x22 * f; f *= id;
            cf[3] += x11 * f; cf[4]  += x12 * f; cf[5]  += x22 * f; f *= id;
            cf[6] += x11 * f; cf[7]  += x12 * f; cf[8]  += x22 * f; f *= id;
            cf[9] += x11 * f; cf[10] += x12 * f; cf[11] += x22 * f;
        }
    }
#pragma unroll
    for (int c = 0; c < 12; ++c) cf[c] = wsum(cf[c]);
    if (lane == 0) {
        double* dw = &dsh[16 + wv * 12];
#pragma unroll
        for (int c = 0; c < 12; ++c) dw[c] = cf[c];
    }
    __syncthreads();
    if (tid < 12) {
        double s = 0;
        for (int w = 0; w < 4; ++w) s += dsh[16 + w * 12 + tid];
        dsh[96 + tid] = s;
    }
    __syncthreads();

    cnt = ish[8];
    const bool nearOK = (cnt <= NL_CAP - 8);
    const float4* l0 = nearOK ? (const float4*)nl0 : (const float4*)sd2;
    const float4* l1 = nearOK ? (const float4*)nl1 : (const float4*)sw1;
    const float4* l2 = nearOK ? (const float4*)nl2 : (const float4*)sw2;
    const int n4 = nearOK ? ish[10] : 512;
    const bool poly = nearOK;
    const double* pcoef = &dsh[96];

    double zg1, zg2, zg3;
    if (wv == 0) {
        int N = lane_evalN32((float)cut2, cut2, n4, l0, l1, l2, pcoef, poly, cS,
                             zg1, zg2, zg3);
        if (lane == 0) ish[9] = N;
    }
    __syncthreads();
    int m = ish[9];
    if (m < 0) m = 0;
    if (m > MAXM) m = MAXM;

    // ---- Phase C: per-lane 65-section (3 rounds + final), f32 evals ----
    for (int k = wv; k < m; k += 4) {
        double klo = 0.0, khi = cut2;
        for (int r = 0; r < 3; ++r) {
            const double w = khi - klo;
            const double td = klo + w * (double)(lane + 1) / 65.0;
            int N = lane_evalN32((float)td, td, n4, l0, l1, l2, pcoef, poly, cS,
                                 zg1, zg2, zg3);
            unsigned long long mask = __ballot(N >= k + 1);
            int j = (mask == 0ull) ? 64 : (__ffsll(mask) - 1);
            double nk = (j == 64) ? khi : (klo + w * (double)(j + 1) / 65.0);
            klo = klo + w * (double)j / 65.0;
            khi = nk;
        }
        const double lam = 0.5 * (klo + khi);
        double g11, g12, g22;
        lane_evalN32((float)lam, lam, n4, l0, l1, l2, pcoef, poly, cS, g11, g12, g22);
        const double m00 = 1.0 + g12, m01 = g11 + cS * g12;
        const double m10 = g22,       m11 = 1.0 + g12 + cS * g22;
        double y1, y2;
        if (m00 * m00 + m01 * m01 >= m10 * m10 + m11 * m11) { y1 = m01; y2 = -m00; }
        else                                                { y1 = m11; y2 = -m10; }
        if (lane == 0) {
            dsh[112 + 3 * k]     = lam;
            dsh[112 + 3 * k + 1] = y2;             // z1
            dsh[112 + 3 * k + 2] = y1 + cS * y2;   // z2
        }
    }
    __syncthreads();

    // ---- Phase D: full eigenvectors + f64 norms (once) ----
    for (int k = 0; k < m; ++k) {
        const double lam = dsh[112 + 3 * k];
        const double z1 = dsh[112 + 3 * k + 1], z2 = dsh[112 + 3 * k + 2];
        double vr[8], pn = 0;
#pragma unroll
        for (int e = 0; e < 8; ++e) {
            double den = (double)d2r[e] - lam;
            if (fabs(den) < 1e-25) den = (den < 0 ? -1e-25 : 1e-25);
            vr[e] = ((double)w1r[e] * z1 + (double)w2r[e] * z2) * frcp(den);
            pn += vr[e] * vr[e];
        }
        pn = wsum(pn);
        if (lane == 0) dsh[160 + wv] = pn;
        __syncthreads();
        double tot = 0;
        for (int w = 0; w < 4; ++w) tot += dsh[160 + w];
        const double inv = 1.0 / sqrt(tot);
        float o0[8];
#pragma unroll
        for (int e = 0; e < 8; ++e) o0[e] = (float)(vr[e] * inv);
        *(float4*)&V[(size_t)k * 2048 + j0]     = *(float4*)&o0[0];
        *(float4*)&V[(size_t)k * 2048 + j0 + 4] = *(float4*)&o0[4];
        __syncthreads();
    }

    if (tid == 0) { hdr[0] = lmax; hdr[1] = cut2; hdr[2] = (double)m; hdr[3] = cS; }
}

// ==================== fat kernel: block 0 = spec, blocks 1..ntiles = GEMM ====================

__global__ __launch_bounds__(256)
void fat_k(const u16* __restrict__ A, const u16* __restrict__ B,
           float* __restrict__ C, int Ndim, int Kdim, int ntiles, int nbx,
           const float* __restrict__ av, const float* __restrict__ pv,
           const float* __restrict__ qv, double* __restrict__ hdr,
           float* __restrict__ V)
{
    __shared__ __align__(16) unsigned char smem[SMEM_BYTES];
    const int bid = blockIdx.x;
    if (bid == 0) {
        spec256(smem, threadIdx.x, av, pv, qv, hdr, V);
        return;
    }
    if (bid - 1 >= ntiles) return;
    const int t = bid - 1;
    gemm_tile((u16*)smem, (u16*)smem + 4096, threadIdx.x,
              t % nbx, t / nbx, A, B, C, Ndim, Kdim);
}

// ==================== wave-per-row fused series kernel (H == 2048) ====================

__global__ __launch_bounds__(256, 2)
void series_k(float* __restrict__ io, const float* __restrict__ hm,
              const float* __restrict__ qv, const float* __restrict__ pv,
              const float* __restrict__ av, const float* __restrict__ delta,
              const float* __restrict__ V, const double* __restrict__ hdr,
              int useTrunc)
{
    const int lane = threadIdx.x & 63;
    const int row = blockIdx.x * 4 + (threadIdx.x >> 6);
    const float d = delta[0];
    const int m = useTrunc ? (int)hdr[2] : 0;

    float q[32], p[32], a[32], t[32], o[32];
    float* iorow = io + (size_t)row * 2048;
#pragma unroll
    for (int cc = 0; cc < 8; ++cc) {
        const int j = cc * 256 + lane * 4;
        *(float4*)&q[cc * 4] = *(const float4*)&qv[j];
        *(float4*)&p[cc * 4] = *(const float4*)&pv[j];
        *(float4*)&a[cc * 4] = *(const float4*)&av[j];
        *(float4*)&t[cc * 4] = *(const float4*)&iorow[j];
    }
#pragma unroll
    for (int e = 0; e < 32; ++e) o[e] = t[e];

    float cf = 1.f;
    for (int k = 1; k <= 13; ++k) {
        float s = 0.f;
#pragma unroll
        for (int e = 0; e < 32; ++e) s += t[e] * q[e];
#pragma unroll
        for (int msk = 32; msk; msk >>= 1) s += __shfl_xor(s, msk, 64);
        cf /= (float)(k + 1);
        const float ds = d * s;
#pragma unroll
        for (int e = 0; e < 32; ++e) { t[e] = d * a[e] * t[e] + ds * p[e]; o[e] += cf * t[e]; }
    }
#pragma unroll
    for (int e = 0; e < 32; ++e) o[e] *= d;

    for (int k = 0; k < m; ++k) {
        const float* vr = V + (size_t)k * 2048;
        float vk[32];
#pragma unroll
        for (int cc = 0; cc < 8; ++cc)
            *(float4*)&vk[cc * 4] = *(const float4*)&vr[cc * 256 + lane * 4];
        float s = 0.f;
#pragma unroll
        for (int e = 0; e < 32; ++e) s += o[e] * vk[e];
#pragma unroll
        for (int msk = 32; msk; msk >>= 1) s += __shfl_xor(s, msk, 64);
#pragma unroll
        for (int e = 0; e < 32; ++e) o[e] -= s * vk[e];
    }

    const float* hrow = hm + (size_t)row * 2048;
#pragma unroll
    for (int cc = 0; cc < 8; ++cc)
        *(float4*)&t[cc * 4] = *(const float4*)&hrow[cc * 256 + lane * 4];
#pragma unroll
    for (int e = 0; e < 32; ++e) o[e] += t[e];
    cf = 1.f;
    for (int k = 1; k <= 14; ++k) {
        float s = 0.f;
#pragma unroll
        for (int e = 0; e < 32; ++e) s += t[e] * q[e];
#pragma unroll
        for (int msk = 32; msk; msk >>= 1) s += __shfl_xor(s, msk, 64);
        cf /= (float)k;
        const float ds = d * s;
#pragma unroll
        for (int e = 0; e < 32; ++e) { t[e] = d * a[e] * t[e] + ds * p[e]; o[e] += cf * t[e]; }
    }
#pragma unroll
    for (int cc = 0; cc < 8; ++cc)
        *(float4*)&iorow[cc * 256 + lane * 4] = *(const float4*)&o[cc * 4];
}

// ==================== host orchestration ====================
// out = h expm(dA)^T + d*(x b^T) phi1(dA^T) (I - P_V);  P_V = truncated
// right-singular subspace of A per jnp.linalg.pinv rcond (exact identity).
// conv -> fat(spec block 0 || 256 GEMM tiles) -> series.

extern "C" void kernel_launch(void* const* d_in, const int* in_sizes, int n_in,
                              void* d_out, int out_size, void* d_ws, size_t ws_size,
                              hipStream_t stream)
{
    const float* hmat  = (const float*)d_in[0];
    const float* xmat  = (const float*)d_in[1];
    const float* adiag = (const float*)d_in[2];
    const float* pvec  = (const float*)d_in[3];
    const float* qvec  = (const float*)d_in[4];
    const float* bmat  = (const float*)d_in[5];
    const float* delta = (const float*)d_in[6];
    float* out = (float*)d_out;

    const int H  = in_sizes[2];
    const int Bb = in_sizes[0] / H;
    const size_t SZ = (size_t)Bb * H;
    const size_t HH = (size_t)H * H;

    double* hdr = (double*)d_ws;
    float* V = (float*)(hdr + 8);
    u16* xb = (u16*)(V + (size_t)MAXM * H);
    u16* bb = xb + SZ;

    const size_t needSpec = 64 + (size_t)MAXM * H * sizeof(float);
    const size_t needFull = needSpec + (SZ + HH) * sizeof(u16);
    const bool doTrunc = (H == 2048) && (ws_size >= needSpec);
    const bool doBf16  = (ws_size >= needFull) && (H % 128 == 0) && (Bb % 128 == 0);

    dim3 blk256(256);
    const int nbx = H / 128;
    const int ntiles = nbx * (Bb / 128);

    if (doBf16) {
        const long nmax = (long)(SZ > HH ? SZ : HH);
        const int cg = (int)((nmax / 4 + 255) / 256);
        conv_k<<<cg, blk256, 0, stream>>>(xmat, bmat, xb, bb, (long)SZ, (long)HH);
        if (doTrunc) {
            fat_k<<<1 + ntiles, blk256, 0, stream>>>(xb, bb, out, H, H, ntiles, nbx,
                                                     adiag, pvec, qvec, hdr, V);
        } else {
            dim3 gg(nbx, Bb / 128);
            bgemm_k<<<gg, blk256, 0, stream>>>(xb, bb, out, H, H);
        }
    } else {
        if (doTrunc)
            fat_k<<<1, blk256, 0, stream>>>(nullptr, nullptr, out, H, H, 0, 1,
                                            adiag, pvec, qvec, hdr, V);
        dim3 gg(H / 64, Bb / 128);
        g_sgemm_k<<<gg, blk256, 0, stream>>>(xmat, bmat, out, Bb, H, H);
    }

    // fused series + projection, in-place on d_out
    series_k<<<Bb / 4, blk256, 0, stream>>>(out, hmat, qvec, pvec, adiag, delta,
                                            V, hdr, doTrunc ? 1 : 0);
}

// Round 11
// 91.218 us; speedup vs baseline: 1.9585x; 1.0022x over previous
//
#include <hip/hip_runtime.h>

#define MAXM 16
#define NL_CAP 256
#define THETA 0.1f
#define SMEM_BYTES 36864

typedef unsigned short u16;
typedef u16 u16x8 __attribute__((ext_vector_type(8)));
typedef u16 u16x4 __attribute__((ext_vector_type(4)));
typedef __bf16 bf16x8 __attribute__((ext_vector_type(8)));
typedef float f32x4 __attribute__((ext_vector_type(4)));

// ==================== f32 -> bf16 (RNE) ====================

__device__ __forceinline__ u16 f2bf(float f) {
    unsigned u = __float_as_uint(f);
    return (u16)((u + 0x7fffu + ((u >> 16) & 1u)) >> 16);
}

__global__ __launch_bounds__(256)
void conv_k(const float* __restrict__ x, const float* __restrict__ b,
            u16* __restrict__ xb, u16* __restrict__ bb, long nx, long nb)
{
    long i = ((long)blockIdx.x * 256 + threadIdx.x) * 4;
    if (i < nx) {
        float4 v = *(const float4*)&x[i];
        u16x4 o = {f2bf(v.x), f2bf(v.y), f2bf(v.z), f2bf(v.w)};
        *(u16x4*)&xb[i] = o;
    }
    if (i < nb) {
        float4 v = *(const float4*)&b[i];
        u16x4 o = {f2bf(v.x), f2bf(v.y), f2bf(v.z), f2bf(v.w)};
        *(u16x4*)&bb[i] = o;
    }
}

// ==================== fast f64 reciprocal (Phase B/D only) ====================

__device__ __forceinline__ double frcp(double den) {
    double r = (double)__builtin_amdgcn_rcpf((float)den);
    return fma(r, fma(-den, r, 1.0), r);
}

// ==================== bf16 MFMA GEMM tile (device fn) ====================
// C[128x128] tile at (bx,by). Kstride = row stride of A/B; Klen = K extent
// to accumulate (split-K: caller pre-offsets A/B and picks the C buffer).

__device__ __forceinline__ void gload_lds16(const void* g, void* l) {
    __builtin_amdgcn_global_load_lds(
        (const __attribute__((address_space(1))) unsigned int*)g,
        (__attribute__((address_space(3))) unsigned int*)l, 16, 0, 0);
}

__device__ __forceinline__ void gemm_tile(u16* Al, u16* Bl, int tid, int bx, int by,
                                          const u16* __restrict__ A,
                                          const u16* __restrict__ B,
                                          float* __restrict__ C,
                                          int Ndim, int Kstride, int Klen)
{
    const int bm = by * 128, bn = bx * 128;
    const int wv = tid >> 6, ln = tid & 63;
    const int wr = (wv >> 1) * 64, wc = (wv & 1) * 64;
    const int fr = ln & 15, fk = (ln >> 4) * 8;

    const int r0 = tid >> 2, c0 = (tid & 3) * 8;
    const u16* Ap0 = A + (size_t)(bm + r0) * Kstride + c0;
    const u16* Ap1 = Ap0 + (size_t)64 * Kstride;
    const u16* Bp0 = B + (size_t)(bn + r0) * Kstride + c0;
    const u16* Bp1 = Bp0 + (size_t)64 * Kstride;
    u16* AlW0 = Al + wv * 512;
    u16* AlW1 = Al + 2048 + wv * 512;
    u16* BlW0 = Bl + wv * 512;
    u16* BlW1 = Bl + 2048 + wv * 512;

    f32x4 acc[4][4];
#pragma unroll
    for (int m = 0; m < 4; ++m)
#pragma unroll
        for (int n = 0; n < 4; ++n) acc[m][n] = (f32x4)0.f;

    for (int kk = 0; kk < Klen; kk += 32) {
        __syncthreads();
        gload_lds16(Ap0 + kk, AlW0);
        gload_lds16(Ap1 + kk, AlW1);
        gload_lds16(Bp0 + kk, BlW0);
        gload_lds16(Bp1 + kk, BlW1);
        __syncthreads();
        u16x8 af[4], bf[4];
#pragma unroll
        for (int m = 0; m < 4; ++m)
            af[m] = *(const u16x8*)&Al[(wr + m * 16 + fr) * 32 + fk];
#pragma unroll
        for (int n = 0; n < 4; ++n)
            bf[n] = *(const u16x8*)&Bl[(wc + n * 16 + fr) * 32 + fk];
#pragma unroll
        for (int m = 0; m < 4; ++m)
#pragma unroll
            for (int n = 0; n < 4; ++n)
                acc[m][n] = __builtin_amdgcn_mfma_f32_16x16x32_bf16(
                    __builtin_bit_cast(bf16x8, af[m]),
                    __builtin_bit_cast(bf16x8, bf[n]), acc[m][n], 0, 0, 0);
    }

    const int crow = (ln >> 4) * 4;
#pragma unroll
    for (int m = 0; m < 4; ++m)
#pragma unroll
        for (int n = 0; n < 4; ++n) {
            const size_t base = (size_t)(bm + wr + m * 16 + crow) * Ndim
                              + bn + wc + n * 16 + fr;
#pragma unroll
            for (int j = 0; j < 4; ++j)
                C[base + (size_t)j * Ndim] = acc[m][n][j];
        }
}

__global__ __launch_bounds__(256)
void bgemm_k(const u16* __restrict__ A, const u16* __restrict__ B,
             float* __restrict__ C, int Ndim, int Kdim)
{
    __shared__ __align__(16) unsigned char smem[SMEM_BYTES];
    gemm_tile((u16*)smem, (u16*)smem + 4096, threadIdx.x,
              blockIdx.x, blockIdx.y, A, B, C, Ndim, Kdim, Kdim);
}

// ==================== f32 fallback GEMM (ws too small) ====================

__global__ __launch_bounds__(256)
void g_sgemm_k(const float* __restrict__ A, const float* __restrict__ B,
               float* __restrict__ C, int Mdim, int Ndim, int Kdim)
{
    __shared__ __align__(16) float As[16][132];
    __shared__ __align__(16) float Bs[16][68];
    const int tid = threadIdx.x;
    const int tx = tid & 15, ty = tid >> 4;
    const int bn = blockIdx.x * 64, bm = blockIdx.y * 128;
    const int lrA = tid >> 1, lcA = (tid & 1) << 3;
    const int lrB = tid >> 2, lcB = (tid & 3) << 2;
    const float* Aptr = A + (size_t)(bm + lrA) * Kdim + lcA;
    const float* Bptr = B + (size_t)(bn + lrB) * Kdim + lcB;
    float4 a0 = *(const float4*)(Aptr);
    float4 a1 = *(const float4*)(Aptr + 4);
    float4 b0 = *(const float4*)(Bptr);
    float acc[8][4];
#pragma unroll
    for (int i = 0; i < 8; ++i)
#pragma unroll
        for (int j = 0; j < 4; ++j) acc[i][j] = 0.f;
    for (int kk = 0; kk < Kdim; kk += 16) {
        __syncthreads();
        As[lcA + 0][lrA] = a0.x; As[lcA + 1][lrA] = a0.y;
        As[lcA + 2][lrA] = a0.z; As[lcA + 3][lrA] = a0.w;
        As[lcA + 4][lrA] = a1.x; As[lcA + 5][lrA] = a1.y;
        As[lcA + 6][lrA] = a1.z; As[lcA + 7][lrA] = a1.w;
        Bs[lcB + 0][lrB] = b0.x; Bs[lcB + 1][lrB] = b0.y;
        Bs[lcB + 2][lrB] = b0.z; Bs[lcB + 3][lrB] = b0.w;
        __syncthreads();
        if (kk + 16 < Kdim) {
            a0 = *(const float4*)(Aptr + kk + 16);
            a1 = *(const float4*)(Aptr + kk + 20);
            b0 = *(const float4*)(Bptr + kk + 16);
        }
#pragma unroll
        for (int k = 0; k < 16; ++k) {
            const float4 av0 = *(const float4*)&As[k][ty * 8];
            const float4 av1 = *(const float4*)&As[k][ty * 8 + 4];
            const float4 bv  = *(const float4*)&Bs[k][tx * 4];
            const float avf[8] = {av0.x, av0.y, av0.z, av0.w, av1.x, av1.y, av1.z, av1.w};
            const float bvf[4] = {bv.x, bv.y, bv.z, bv.w};
#pragma unroll
            for (int i = 0; i < 8; ++i)
#pragma unroll
                for (int j = 0; j < 4; ++j) acc[i][j] += avf[i] * bvf[j];
        }
    }
#pragma unroll
    for (int i = 0; i < 8; ++i) {
        const int r = bm + ty * 8 + i;
        float4 v = {acc[i][0], acc[i][1], acc[i][2], acc[i][3]};
        *(float4*)&C[(size_t)r * Ndim + bn + tx * 4] = v;
    }
}

// ==================== spectral solve (device fn, 256 thr, H == 2048) ====================
// Haynsworth inertia on A^T A = D^2 + W S W^T; hot secular evals in F32.

__device__ __forceinline__ double wsum(double x) {
#pragma unroll
    for (int m = 32; m; m >>= 1) x += __shfl_xor(x, m, 64);
    return x;
}
__device__ __forceinline__ float wsumf(float x) {
#pragma unroll
    for (int m = 32; m; m >>= 1) x += __shfl_xor(x, m, 64);
    return x;
}

__device__ __forceinline__ int inert(double s11, double s12, double s22,
                                     double dc, double cS)
{
    double b00 = cS - s11, b01 = -1.0 - s12, b11 = -s22;   // -S^{-1} - G
    double det = b00 * b11 - b01 * b01, tr = b00 + b11;
    int neg = (det > 0.0) ? ((tr < 0.0) ? 2 : 0) : 1;
    return (int)(dc + 0.5) + neg - 1;
}

__device__ __forceinline__ int lane_evalN32(float tf, double td, int n4,
    const float4* l0, const float4* l1, const float4* l2,
    const double* pc, bool poly, double cS,
    double& g11o, double& g12o, double& g22o)
{
    float s11 = 0.f, s12 = 0.f, s22 = 0.f, dc = 0.f;
#pragma unroll 2
    for (int i = 0; i < n4; ++i) {
        const float4 d4 = l0[i], x4 = l1[i], y4 = l2[i];
        const float dd[4] = {d4.x, d4.y, d4.z, d4.w};
        const float xx[4] = {x4.x, x4.y, x4.z, x4.w};
        const float yy[4] = {y4.x, y4.y, y4.z, y4.w};
#pragma unroll
        for (int e = 0; e < 4; ++e) {
            float den = dd[e] - tf;
            float mag = fmaxf(fabsf(den), 1e-30f);
            den = (den < 0.f) ? -mag : mag;
            const float inv = __builtin_amdgcn_rcpf(den);
            s11 = fmaf(xx[e] * xx[e], inv, s11);
            s12 = fmaf(xx[e] * yy[e], inv, s12);
            s22 = fmaf(yy[e] * yy[e], inv, s22);
            if (dd[e] < tf) dc += 1.f;
        }
    }
    double S11 = (double)s11, S12 = (double)s12, S22 = (double)s22;
    if (poly) {
        S11 += pc[0] + td * (pc[3] + td * (pc[6] + td * pc[9]));
        S12 += pc[1] + td * (pc[4] + td * (pc[7] + td * pc[10]));
        S22 += pc[2] + td * (pc[5] + td * (pc[8] + td * pc[11]));
    }
    g11o = S11; g12o = S12; g22o = S22;
    return inert(S11, S12, S22, (double)dc, cS);
}

__device__ void spec256(unsigned char* smem, int tid,
                        const float* __restrict__ av, const float* __restrict__ pv,
                        const float* __restrict__ qv, double* __restrict__ hdr,
                        float* __restrict__ V)
{
    float* sd2 = (float*)smem;          // 2048
    float* sw1 = sd2 + 2048;
    float* sw2 = sw1 + 2048;
    float* nl0 = sw2 + 2048;            // NL_CAP each
    float* nl1 = nl0 + NL_CAP;
    float* nl2 = nl1 + NL_CAP;
    double* dsh = (double*)(nl2 + NL_CAP);   // 192 doubles
    int* ish = (int*)(dsh + 192);            // 16 ints

    const int lane = tid & 63, wv = tid >> 6;
    const int j0 = tid * 8;

    float d2r[8], w1r[8], w2r[8];
    double cS = 0, n1 = 0, n2 = 0, mx = 0;
#pragma unroll
    for (int h = 0; h < 2; ++h) {
        float4 aa = *(const float4*)&av[j0 + h * 4];
        float4 pp = *(const float4*)&pv[j0 + h * 4];
        float4 qq = *(const float4*)&qv[j0 + h * 4];
        const float a4[4] = {aa.x, aa.y, aa.z, aa.w};
        const float p4[4] = {pp.x, pp.y, pp.z, pp.w};
        const float q4[4] = {qq.x, qq.y, qq.z, qq.w};
#pragma unroll
        for (int e = 0; e < 4; ++e) {
            const int ix = h * 4 + e;
            d2r[ix] = a4[e] * a4[e];
            w1r[ix] = a4[e] * p4[e];
            w2r[ix] = q4[e];
            sd2[j0 + ix] = d2r[ix]; sw1[j0 + ix] = w1r[ix]; sw2[j0 + ix] = w2r[ix];
            cS += (double)p4[e] * p4[e];
            n1 += (double)w1r[ix] * w1r[ix];
            n2 += (double)w2r[ix] * w2r[ix];
            mx = fmax(mx, (double)d2r[ix]);
        }
    }
    cS = wsum(cS); n1 = wsum(n1); n2 = wsum(n2);
#pragma unroll
    for (int m_ = 32; m_; m_ >>= 1) mx = fmax(mx, __shfl_xor(mx, m_, 64));
    __syncthreads();
    if (lane == 0) { dsh[wv] = cS; dsh[4 + wv] = n1; dsh[8 + wv] = n2; dsh[12 + wv] = mx; }
    __syncthreads();
    cS = 0; n1 = 0; n2 = 0; mx = 0;
    for (int w = 0; w < 4; ++w) {
        cS += dsh[w]; n1 += dsh[4 + w]; n2 += dsh[8 + w];
        mx = fmax(mx, dsh[12 + w]);
    }
    __syncthreads();

    // ---- Phase A: lambda_max 5-section x 8 rounds, f32 scans ----
    double lo = 0.0;
    double hi = mx + 0.5 * (cS + sqrt(cS * cS + 4.0)) * (n1 + n2) + 1.0;
    for (int r = 0; r < 8; ++r) {
        const double td = lo + (hi - lo) * (double)(wv + 1) / 5.0;
        const float tf = (float)td;
        float s11 = 0.f, s12 = 0.f, s22 = 0.f, dc = 0.f;
        for (int i4 = lane; i4 < 512; i4 += 64) {
            const float4 dd = ((const float4*)sd2)[i4];
            const float4 e1 = ((const float4*)sw1)[i4];
            const float4 e2 = ((const float4*)sw2)[i4];
            const float df[4] = {dd.x, dd.y, dd.z, dd.w};
            const float f1[4] = {e1.x, e1.y, e1.z, e1.w};
            const float f2[4] = {e2.x, e2.y, e2.z, e2.w};
#pragma unroll
            for (int e = 0; e < 4; ++e) {
                float den = df[e] - tf;
                float mag = fmaxf(fabsf(den), 1e-30f);
                den = (den < 0.f) ? -mag : mag;
                const float inv = __builtin_amdgcn_rcpf(den);
                s11 = fmaf(f1[e] * f1[e], inv, s11);
                s12 = fmaf(f1[e] * f2[e], inv, s12);
                s22 = fmaf(f2[e] * f2[e], inv, s22);
                if (df[e] < tf) dc += 1.f;
            }
        }
        s11 = wsumf(s11); s12 = wsumf(s12); s22 = wsumf(s22); dc = wsumf(dc);
        if (lane == 0)
            ish[wv] = inert((double)s11, (double)s12, (double)s22, (double)dc, cS);
        __syncthreads();
        double nlo = lo, nhi = hi;
        for (int i = 0; i < 4; ++i) {
            double ti = lo + (hi - lo) * (double)(i + 1) / 5.0;
            if (ish[i] >= 2048) { if (ti < nhi) nhi = ti; }
            else                { if (ti > nlo) nlo = ti; }
        }
        lo = nlo; hi = nhi;
        __syncthreads();
    }
    const double lmax = 0.5 * (lo + hi);
    const double rc = 10.0 * 2048.0 * 1.1920928955078125e-07;
    const double cut2 = rc * rc * lmax;

    // ---- Phase B: deterministic near-list compaction + far Taylor coeffs ----
    int flags = 0, lc = 0;
#pragma unroll
    for (int e = 0; e < 8; ++e)
        if (d2r[e] < THETA) { flags |= (1 << e); ++lc; }
    int sc = lc;
#pragma unroll
    for (int off = 1; off < 64; off <<= 1) {
        int y = __shfl_up(sc, off, 64);
        if (lane >= off) sc += y;
    }
    const int wtot = __shfl(sc, 63, 64);
    const int excl = sc - lc;
    if (lane == 0) ish[4 + wv] = wtot;
    __syncthreads();
    int base = excl;
    for (int w = 0; w < wv; ++w) base += ish[4 + w];
    int cnt = 0;
    for (int w = 0; w < 4; ++w) cnt += ish[4 + w];
    {
        int pos = base;
#pragma unroll
        for (int e = 0; e < 8; ++e) {
            if (flags & (1 << e)) {
                if (pos < NL_CAP) { nl0[pos] = d2r[e]; nl1[pos] = w1r[e]; nl2[pos] = w2r[e]; }
                ++pos;
            }
        }
    }
    const int cntPad = (cnt + 7) & ~7;
    if (tid == 0) {
        for (int i = cnt; i < cntPad && i < NL_CAP; ++i) {
            nl0[i] = 1e30f; nl1[i] = 0.f; nl2[i] = 0.f;
        }
        ish[8] = cnt; ish[10] = cntPad >> 2;
    }

    double cf[12];
#pragma unroll
    for (int c = 0; c < 12; ++c) cf[c] = 0;
#pragma unroll
    for (int e = 0; e < 8; ++e) {
        if (d2r[e] >= THETA) {
            double id = frcp((double)d2r[e]);
            double b1 = (double)w1r[e], b2 = (double)w2r[e];
            double x11 = b1 * b1, x12 = b1 * b2, x22 = b2 * b2;
            double f = id;
            cf[0] += x11 * f; cf[1]  += x12 * f; cf[2]  += x22 * f; f *= id;
            cf[3] += x11 * f; cf[4]  += x12 * f; cf[5]  += x22 * f; f *= id;
            cf[6] += x11 * f; cf[7]  += x12 * f; cf[8]  += x22 * f; f *= id;
            cf[9] += x11 * f; cf[10] += x12 * f; cf[11] += x22 * f;
        }
    }
#pragma unroll
    for (int c = 0; c < 12; ++c) cf[c] = wsum(cf[c]);
    if (lane == 0) {
        double* dw = &dsh[16 + wv * 12];
#pragma unroll
        for (int c = 0; c < 12; ++c) dw[c] = cf[c];
    }
    __syncthreads();
    if (tid < 12) {
        double s = 0;
        for (int w = 0; w < 4; ++w) s += dsh[16 + w * 12 + tid];
        dsh[96 + tid] = s;
    }
    __syncthreads();

    cnt = ish[8];
    const bool nearOK = (cnt <= NL_CAP - 8);
    const float4* l0 = nearOK ? (const float4*)nl0 : (const float4*)sd2;
    const float4* l1 = nearOK ? (const float4*)nl1 : (const float4*)sw1;
    const float4* l2 = nearOK ? (const float4*)nl2 : (const float4*)sw2;
    const int n4 = nearOK ? ish[10] : 512;
    const bool poly = nearOK;
    const double* pcoef = &dsh[96];

    double zg1, zg2, zg3;
    if (wv == 0) {
        int N = lane_evalN32((float)cut2, cut2, n4, l0, l1, l2, pcoef, poly, cS,
                             zg1, zg2, zg3);
        if (lane == 0) ish[9] = N;
    }
    __syncthreads();
    int m = ish[9];
    if (m < 0) m = 0;
    if (m > MAXM) m = MAXM;

    // ---- Phase C: per-lane 65-section (3 rounds + final), f32 evals ----
    for (int k = wv; k < m; k += 4) {
        double klo = 0.0, khi = cut2;
        for (int r = 0; r < 3; ++r) {
            const double w = khi - klo;
            const double td = klo + w * (double)(lane + 1) / 65.0;
            int N = lane_evalN32((float)td, td, n4, l0, l1, l2, pcoef, poly, cS,
                                 zg1, zg2, zg3);
            unsigned long long mask = __ballot(N >= k + 1);
            int j = (mask == 0ull) ? 64 : (__ffsll(mask) - 1);
            double nk = (j == 64) ? khi : (klo + w * (double)(j + 1) / 65.0);
            klo = klo + w * (double)j / 65.0;
            khi = nk;
        }
        const double lam = 0.5 * (klo + khi);
        double g11, g12, g22;
        lane_evalN32((float)lam, lam, n4, l0, l1, l2, pcoef, poly, cS, g11, g12, g22);
        const double m00 = 1.0 + g12, m01 = g11 + cS * g12;
        const double m10 = g22,       m11 = 1.0 + g12 + cS * g22;
        double y1, y2;
        if (m00 * m00 + m01 * m01 >= m10 * m10 + m11 * m11) { y1 = m01; y2 = -m00; }
        else                                                { y1 = m11; y2 = -m10; }
        if (lane == 0) {
            dsh[112 + 3 * k]     = lam;
            dsh[112 + 3 * k + 1] = y2;             // z1
            dsh[112 + 3 * k + 2] = y1 + cS * y2;   // z2
        }
    }
    __syncthreads();

    // ---- Phase D: full eigenvectors + f64 norms ----
    for (int k = 0; k < m; ++k) {
        const double lam = dsh[112 + 3 * k];
        const double z1 = dsh[112 + 3 * k + 1], z2 = dsh[112 + 3 * k + 2];
        double vr[8], pn = 0;
#pragma unroll
        for (int e = 0; e < 8; ++e) {
            double den = (double)d2r[e] - lam;
            if (fabs(den) < 1e-25) den = (den < 0 ? -1e-25 : 1e-25);
            vr[e] = ((double)w1r[e] * z1 + (double)w2r[e] * z2) * frcp(den);
            pn += vr[e] * vr[e];
        }
        pn = wsum(pn);
        if (lane == 0) dsh[160 + wv] = pn;
        __syncthreads();
        double tot = 0;
        for (int w = 0; w < 4; ++w) tot += dsh[160 + w];
        const double inv = 1.0 / sqrt(tot);
        float o0[8];
#pragma unroll
        for (int e = 0; e < 8; ++e) o0[e] = (float)(vr[e] * inv);
        *(float4*)&V[(size_t)k * 2048 + j0]     = *(float4*)&o0[0];
        *(float4*)&V[(size_t)k * 2048 + j0 + 4] = *(float4*)&o0[4];
        __syncthreads();
    }

    if (tid == 0) { hdr[0] = lmax; hdr[1] = cut2; hdr[2] = (double)m; hdr[3] = cS; }
}

// ==================== fat kernel: block 0 = spec, rest = split-K GEMM ====================
// nsplit K-chunks per output tile; chunk ks writes Cp[ks] (C0 = d_out,
// C1 = ws partial). series_k sums the partials in fixed order (deterministic).

__global__ __launch_bounds__(256)
void fat_k(const u16* __restrict__ A, const u16* __restrict__ B,
           float* __restrict__ C0, float* __restrict__ C1,
           int Ndim, int Kdim, int ntiles, int nbx, int nsplit,
           const float* __restrict__ av, const float* __restrict__ pv,
           const float* __restrict__ qv, double* __restrict__ hdr,
           float* __restrict__ V)
{
    __shared__ __align__(16) unsigned char smem[SMEM_BYTES];
    const int bid = blockIdx.x;
    if (bid == 0) {
        spec256(smem, threadIdx.x, av, pv, qv, hdr, V);
        return;
    }
    const int t = bid - 1;
    if (t >= ntiles * nsplit) return;
    const int ks = t / ntiles;
    const int tt = t - ks * ntiles;
    const int Klen = Kdim / nsplit;
    gemm_tile((u16*)smem, (u16*)smem + 4096, threadIdx.x,
              tt % nbx, tt / nbx,
              A + (size_t)ks * Klen, B + (size_t)ks * Klen,
              ks ? C1 : C0, Ndim, Kdim, Klen);
}

// ==================== wave-per-row fused series kernel (H == 2048) ====================
// io (+ io2 if addP) holds U = x b^T on entry; on exit io = out.

__global__ __launch_bounds__(256, 2)
void series_k(float* __restrict__ io, const float* __restrict__ io2, int addP,
              const float* __restrict__ hm,
              const float* __restrict__ qv, const float* __restrict__ pv,
              const float* __restrict__ av, const float* __restrict__ delta,
              const float* __restrict__ V, const double* __restrict__ hdr,
              int useTrunc)
{
    const int lane = threadIdx.x & 63;
    const int row = blockIdx.x * 4 + (threadIdx.x >> 6);
    const float d = delta[0];
    const int m = useTrunc ? (int)hdr[2] : 0;

    float q[32], p[32], a[32], t[32], o[32];
    float* iorow = io + (size_t)row * 2048;
    const float* io2row = io2 + (size_t)row * 2048;
#pragma unroll
    for (int cc = 0; cc < 8; ++cc) {
        const int j = cc * 256 + lane * 4;
        *(float4*)&q[cc * 4] = *(const float4*)&qv[j];
        *(float4*)&p[cc * 4] = *(const float4*)&pv[j];
        *(float4*)&a[cc * 4] = *(const float4*)&av[j];
        float4 u0 = *(const float4*)&iorow[j];
        if (addP) {
            const float4 u1 = *(const float4*)&io2row[j];
            u0.x += u1.x; u0.y += u1.y; u0.z += u1.z; u0.w += u1.w;
        }
        *(float4*)&t[cc * 4] = u0;
    }
#pragma unroll
    for (int e = 0; e < 32; ++e) o[e] = t[e];

    float cf = 1.f;
    for (int k = 1; k <= 13; ++k) {
        float s = 0.f;
#pragma unroll
        for (int e = 0; e < 32; ++e) s += t[e] * q[e];
#pragma unroll
        for (int msk = 32; msk; msk >>= 1) s += __shfl_xor(s, msk, 64);
        cf /= (float)(k + 1);
        const float ds = d * s;
#pragma unroll
        for (int e = 0; e < 32; ++e) { t[e] = d * a[e] * t[e] + ds * p[e]; o[e] += cf * t[e]; }
    }
#pragma unroll
    for (int e = 0; e < 32; ++e) o[e] *= d;

    for (int k = 0; k < m; ++k) {
        const float* vr = V + (size_t)k * 2048;
        float vk[32];
#pragma unroll
        for (int cc = 0; cc < 8; ++cc)
            *(float4*)&vk[cc * 4] = *(const float4*)&vr[cc * 256 + lane * 4];
        float s = 0.f;
#pragma unroll
        for (int e = 0; e < 32; ++e) s += o[e] * vk[e];
#pragma unroll
        for (int msk = 32; msk; msk >>= 1) s += __shfl_xor(s, msk, 64);
#pragma unroll
        for (int e = 0; e < 32; ++e) o[e] -= s * vk[e];
    }

    const float* hrow = hm + (size_t)row * 2048;
#pragma unroll
    for (int cc = 0; cc < 8; ++cc)
        *(float4*)&t[cc * 4] = *(const float4*)&hrow[cc * 256 + lane * 4];
#pragma unroll
    for (int e = 0; e < 32; ++e) o[e] += t[e];
    cf = 1.f;
    for (int k = 1; k <= 14; ++k) {
        float s = 0.f;
#pragma unroll
        for (int e = 0; e < 32; ++e) s += t[e] * q[e];
#pragma unroll
        for (int msk = 32; msk; msk >>= 1) s += __shfl_xor(s, msk, 64);
        cf /= (float)k;
        const float ds = d * s;
#pragma unroll
        for (int e = 0; e < 32; ++e) { t[e] = d * a[e] * t[e] + ds * p[e]; o[e] += cf * t[e]; }
    }
#pragma unroll
    for (int cc = 0; cc < 8; ++cc)
        *(float4*)&iorow[cc * 256 + lane * 4] = *(const float4*)&o[cc * 4];
}

// ==================== host orchestration ====================
// out = h expm(dA)^T + d*(x b^T) phi1(dA^T) (I - P_V);  P_V = truncated
// right-singular subspace of A per jnp.linalg.pinv rcond (exact identity).
// conv -> fat(spec block 0 || split-K GEMM, 2 blocks/CU) -> series(sum partials).

extern "C" void kernel_launch(void* const* d_in, const int* in_sizes, int n_in,
                              void* d_out, int out_size, void* d_ws, size_t ws_size,
                              hipStream_t stream)
{
    const float* hmat  = (const float*)d_in[0];
    const float* xmat  = (const float*)d_in[1];
    const float* adiag = (const float*)d_in[2];
    const float* pvec  = (const float*)d_in[3];
    const float* qvec  = (const float*)d_in[4];
    const float* bmat  = (const float*)d_in[5];
    const float* delta = (const float*)d_in[6];
    float* out = (float*)d_out;

    const int H  = in_sizes[2];
    const int Bb = in_sizes[0] / H;
    const size_t SZ = (size_t)Bb * H;
    const size_t HH = (size_t)H * H;

    double* hdr = (double*)d_ws;
    float* V = (float*)(hdr + 8);
    u16* xb = (u16*)(V + (size_t)MAXM * H);
    u16* bb = xb + SZ;
    float* C1 = (float*)(bb + HH);

    const size_t needSpec  = 64 + (size_t)MAXM * H * sizeof(float);
    const size_t needFull  = needSpec + (SZ + HH) * sizeof(u16);
    const size_t needSplit = needFull + SZ * sizeof(float);
    const bool doTrunc = (H == 2048) && (ws_size >= needSpec);
    const bool doBf16  = (ws_size >= needFull) && (H % 128 == 0) && (Bb % 128 == 0);
    const bool doSplit = doBf16 && doTrunc && (ws_size >= needSplit) && (H % 64 == 0);

    dim3 blk256(256);
    const int nbx = H / 128;
    const int ntiles = nbx * (Bb / 128);

    if (doBf16) {
        const long nmax = (long)(SZ > HH ? SZ : HH);
        const int cg = (int)((nmax / 4 + 255) / 256);
        conv_k<<<cg, blk256, 0, stream>>>(xmat, bmat, xb, bb, (long)SZ, (long)HH);
        if (doTrunc) {
            const int nsplit = doSplit ? 2 : 1;
            fat_k<<<1 + ntiles * nsplit, blk256, 0, stream>>>(
                xb, bb, out, C1, H, H, ntiles, nbx, nsplit,
                adiag, pvec, qvec, hdr, V);
        } else {
            dim3 gg(nbx, Bb / 128);
            bgemm_k<<<gg, blk256, 0, stream>>>(xb, bb, out, H, H);
        }
    } else {
        if (doTrunc)
            fat_k<<<1, blk256, 0, stream>>>(nullptr, nullptr, out, nullptr,
                                            H, H, 0, 1, 1,
                                            adiag, pvec, qvec, hdr, V);
        dim3 gg(H / 64, Bb / 128);
        g_sgemm_k<<<gg, blk256, 0, stream>>>(xmat, bmat, out, Bb, H, H);
    }

    // fused series + projection (+ split-K partial sum), in-place on d_out
    series_k<<<Bb / 4, blk256, 0, stream>>>(out, doSplit ? C1 : out,
                                            doSplit ? 1 : 0,
                                            hmat, qvec, pvec, adiag, delta,
                                            V, hdr, doTrunc ? 1 : 0);
}